// Round 5
// baseline (2353.797 us; speedup 1.0000x reference)
//
#include <hip/hip_runtime.h>
#include <hip/hip_bf16.h>

// GeniePath: 2x GAT(H=1,D=128) + LSTM step. N=100000, E=1600000, D=OUT=128.
// Device dtypes (established empirically over rounds 0-4):
//   inputs  : f32 (probe-verified; bf16 reads -> NaN)
//   output  : f32  [h1 (N*128)] [h1 (N*128)] [c1 (N*128)]  (out_npz ~142MB = f32)
//
// Scratch: d_ws = rst f32 (51.2MB) + WT f32 (0.5MB).
// Transients (feat, ebuf, el, er, mkey, ssum ~59.3MB) live inside d_out
// (153.6MB): each fully written before read every call; lstm_kernel (reads
// only ws + inputs) overwrites all of d_out at the end.

#define D 128
#define NEG_SLOPE 0.2f

// ---------------- feat = x @ W  (W f32 [128][128] row-major) ----------------
#define FT 16
__global__ __launch_bounds__(256) void feat_kernel(const float* __restrict__ xin,
                                                   const float* __restrict__ W,
                                                   float* __restrict__ feat, int N_) {
    __shared__ float xt[FT][D];
    int bn = blockIdx.x * FT;
    int tid = threadIdx.x;
    for (int idx = tid; idx < FT * (D / 4); idx += 256) {
        int n = idx >> 5, q = idx & 31;
        int gn = bn + n;
        float4 v = make_float4(0.f, 0.f, 0.f, 0.f);
        if (gn < N_) v = ((const float4*)(xin + (size_t)gn * D))[q];
        ((float4*)xt[n])[q] = v;
    }
    __syncthreads();
    int j = tid & 127;
    int h = tid >> 7;  // 0 or 1
    float acc[8];
#pragma unroll
    for (int p = 0; p < 8; ++p) acc[p] = 0.f;
    for (int k = 0; k < D; k += 4) {
        float w0 = W[(k + 0) * D + j];
        float w1 = W[(k + 1) * D + j];
        float w2 = W[(k + 2) * D + j];
        float w3 = W[(k + 3) * D + j];
#pragma unroll
        for (int p = 0; p < 8; ++p) {
            int n = h + 2 * p;
            float4 xv = *(const float4*)&xt[n][k];
            acc[p] += xv.x * w0 + xv.y * w1 + xv.z * w2 + xv.w * w3;
        }
    }
#pragma unroll
    for (int p = 0; p < 8; ++p) {
        int n = h + 2 * p;
        int gn = bn + n;
        if (gn < N_) feat[(size_t)gn * D + j] = acc[p];
    }
}

// ---------------- el/er: one wave per node ----------------
__global__ __launch_bounds__(256) void eler_kernel(const float* __restrict__ feat,
                                                   const float* __restrict__ al,
                                                   const float* __restrict__ ar,
                                                   float* __restrict__ el,
                                                   float* __restrict__ er, int N_) {
    int gw = (int)((blockIdx.x * 256 + threadIdx.x) >> 6);
    int lane = threadIdx.x & 63;
    if (gw >= N_) return;
    const float* f = feat + (size_t)gw * D;
    float a = f[lane], b = f[lane + 64];
    float pl = a * al[lane] + b * al[lane + 64];
    float pr = a * ar[lane] + b * ar[lane + 64];
#pragma unroll
    for (int m = 32; m; m >>= 1) {
        pl += __shfl_xor(pl, m);
        pr += __shfl_xor(pr, m);
    }
    if (lane == 0) { el[gw] = pl; er[gw] = pr; }
}

// ---------------- init per-node state ----------------
__global__ void init_kernel(float* __restrict__ rst, unsigned int* __restrict__ mkey,
                            float* __restrict__ ssum, int N_) {
    int total = N_ * D;
    for (int i = blockIdx.x * blockDim.x + threadIdx.x; i < total;
         i += gridDim.x * blockDim.x) {
        rst[i] = 0.f;
        if (i < N_) { mkey[i] = 0u; ssum[i] = 0.f; }
    }
}

// monotonic float->uint key
__device__ __forceinline__ unsigned int fkey(float v) {
    unsigned int b = __float_as_uint(v);
    return (b & 0x80000000u) ? ~b : (b | 0x80000000u);
}
__device__ __forceinline__ float fkey_inv(unsigned int k) {
    return (k & 0x80000000u) ? __uint_as_float(k ^ 0x80000000u) : __uint_as_float(~k);
}

// ---------------- edge pass 1: e + segment max ----------------
__global__ __launch_bounds__(256) void edge1_kernel(const int* __restrict__ src,
                                                    const int* __restrict__ dst,
                                                    const float* __restrict__ el,
                                                    const float* __restrict__ er,
                                                    float* __restrict__ ebuf,
                                                    unsigned int* __restrict__ mkey, int E_) {
    int i = blockIdx.x * 256 + threadIdx.x;
    if (i >= E_) return;
    int s = src[i], d = dst[i];
    float v = el[s] + er[d];
    v = v > 0.f ? v : NEG_SLOPE * v;
    ebuf[i] = v;
    atomicMax(mkey + d, fkey(v));
}

// ---------------- edge pass 2: ex = exp(e - m[dst]); ssum += ex ----------------
__global__ __launch_bounds__(256) void edge2_kernel(const int* __restrict__ dst,
                                                    float* __restrict__ ebuf,
                                                    const unsigned int* __restrict__ mkey,
                                                    float* __restrict__ ssum, int E_) {
    int i = blockIdx.x * 256 + threadIdx.x;
    if (i >= E_) return;
    int d = dst[i];
    float m = fkey_inv(mkey[d]);
    float ex = expf(ebuf[i] - m);
    ebuf[i] = ex;
    atomicAdd(ssum + d, ex);
}

// ---------------- edge pass 3: rst[dst] += feat[src] * alpha ----------------
__global__ __launch_bounds__(256) void edge3_kernel(const int* __restrict__ src,
                                                    const int* __restrict__ dst,
                                                    const float* __restrict__ ebuf,
                                                    const float* __restrict__ ssum,
                                                    const float* __restrict__ feat,
                                                    float* __restrict__ rst, int E_) {
    int gid = blockIdx.x * 256 + threadIdx.x;
    int e = gid >> 6, lane = gid & 63;
    if (e >= E_) return;
    int s = src[e], d = dst[e];
    float alpha = ebuf[e] / ssum[d];
    const float* f = feat + (size_t)s * D;
    float* r = rst + (size_t)d * D;
    atomicAdd(r + lane, f[lane] * alpha);
    atomicAdd(r + lane + 64, f[lane + 64] * alpha);
}

// ---------------- bias add (in place) ----------------
__global__ void bias_kernel(float* __restrict__ rst, const float* __restrict__ bias, int total) {
    for (int i = blockIdx.x * blockDim.x + threadIdx.x; i < total;
         i += gridDim.x * blockDim.x)
        rst[i] += bias[i & 127];
}

// ---------------- LSTM weight transpose: WT[k][j] = Wcat[j][k] ----------------
__global__ void wprep_kernel(const float* __restrict__ W_ih, const float* __restrict__ W_hh,
                             float* __restrict__ WT) {
    int idx = blockIdx.x * 256 + threadIdx.x;  // 256*512 elements
    if (idx >= 256 * 512) return;
    int j = idx & 511, k = idx >> 9;
    float v = (k < 128) ? W_ih[j * 128 + k] : W_hh[j * 128 + (k - 128)];
    WT[k * 512 + j] = v;
}

// ---------------- fused LSTM (all f32), writes f32 outputs ----------------
#define LT 16
__global__ __launch_bounds__(256) void lstm_kernel(const float* __restrict__ x2,
                                                   const float* __restrict__ h0,
                                                   const float* __restrict__ c0,
                                                   const float* __restrict__ WT,
                                                   const float* __restrict__ b_ih,
                                                   const float* __restrict__ b_hh,
                                                   float* __restrict__ out, int N_) {
    __shared__ float xh[LT][256];
    __shared__ float gbuf[LT][512];
    int bn = blockIdx.x * LT;
    int tid = threadIdx.x;
    // x2 rows -> xh[n][0:128], h0 rows -> xh[n][128:256]
    for (int idx = tid; idx < LT * 64; idx += 256) {
        int n = idx >> 6, q = idx & 63;
        int gn = bn + n;
        float4 v = make_float4(0.f, 0.f, 0.f, 0.f);
        if (gn < N_) {
            if (q < 32) v = ((const float4*)(x2 + (size_t)gn * D))[q];
            else        v = ((const float4*)(h0 + (size_t)gn * D))[q - 32];
        }
        ((float4*)xh[n])[q] = v;
    }
    __syncthreads();
    float acc0[LT], acc1[LT];
#pragma unroll
    for (int n = 0; n < LT; ++n) { acc0[n] = 0.f; acc1[n] = 0.f; }
    for (int k = 0; k < 256; k += 4) {
        float w00 = WT[(k + 0) * 512 + tid];
        float w01 = WT[(k + 1) * 512 + tid];
        float w02 = WT[(k + 2) * 512 + tid];
        float w03 = WT[(k + 3) * 512 + tid];
        float w10 = WT[(k + 0) * 512 + tid + 256];
        float w11 = WT[(k + 1) * 512 + tid + 256];
        float w12 = WT[(k + 2) * 512 + tid + 256];
        float w13 = WT[(k + 3) * 512 + tid + 256];
#pragma unroll
        for (int n = 0; n < LT; ++n) {
            float4 xv = *(const float4*)&xh[n][k];
            acc0[n] += xv.x * w00 + xv.y * w01 + xv.z * w02 + xv.w * w03;
            acc1[n] += xv.x * w10 + xv.y * w11 + xv.z * w12 + xv.w * w13;
        }
    }
    float bs0 = b_ih[tid] + b_hh[tid];
    float bs1 = b_ih[tid + 256] + b_hh[tid + 256];
#pragma unroll
    for (int n = 0; n < LT; ++n) {
        gbuf[n][tid] = acc0[n] + bs0;
        gbuf[n][tid + 256] = acc1[n] + bs1;
    }
    __syncthreads();
    size_t NO = (size_t)N_ * D;
    for (int idx = tid; idx < LT * D; idx += 256) {
        int n = idx >> 7, dd = idx & 127;
        int gn = bn + n;
        if (gn >= N_) continue;
        float iv = gbuf[n][dd];
        float fv = gbuf[n][128 + dd];
        float gv = gbuf[n][256 + dd];
        float ov = gbuf[n][384 + dd];
        float c0v = c0[(size_t)gn * D + dd];
        float ig = 1.f / (1.f + expf(-iv));
        float fg = 1.f / (1.f + expf(-fv));
        float og = 1.f / (1.f + expf(-ov));
        float gg = tanhf(gv);
        float c1 = fg * c0v + ig * gg;
        float h1 = og * tanhf(c1);
        size_t o = (size_t)gn * D + dd;
        out[o] = h1;
        out[NO + o] = h1;
        out[2 * NO + o] = c1;
    }
}

extern "C" void kernel_launch(void* const* d_in, const int* in_sizes, int n_in,
                              void* d_out, int out_size, void* d_ws, size_t ws_size,
                              hipStream_t stream) {
    const float* x      = (const float*)d_in[0];
    const float* h      = (const float*)d_in[1];
    const float* c      = (const float*)d_in[2];
    const int*   src0   = (const int*)d_in[3];
    const int*   dst0   = (const int*)d_in[4];
    const int*   src1   = (const int*)d_in[5];
    const int*   dst1   = (const int*)d_in[6];
    const float* W      = (const float*)d_in[7];
    const float* attn_l = (const float*)d_in[8];
    const float* attn_r = (const float*)d_in[9];
    const float* gbias  = (const float*)d_in[10];
    const float* W_ih   = (const float*)d_in[11];
    const float* W_hh   = (const float*)d_in[12];
    const float* b_ih   = (const float*)d_in[13];
    const float* b_hh   = (const float*)d_in[14];
    float* out = (float*)d_out;

    const int N_ = in_sizes[1] / D;  // h is (1,N,128)
    const int E_ = in_sizes[3];

    // ---- transients carved out of d_out (3*N*D*4 = 153.6MB; all dead before
    //      lstm_kernel rewrites every output element) ----
    char* ob = (char*)d_out;
    size_t ooff = 0;
    auto oalloc = [&](size_t nbytes) {
        void* p = ob + ooff;
        ooff += (nbytes + 255) & ~(size_t)255;
        return p;
    };
    float*        feat = (float*)oalloc((size_t)N_ * D * 4);   // 51.2MB
    float*        ebuf = (float*)oalloc((size_t)E_ * 4);       //  6.4MB
    float*        el   = (float*)oalloc((size_t)N_ * 4);
    float*        er   = (float*)oalloc((size_t)N_ * 4);
    unsigned int* mkey = (unsigned int*)oalloc((size_t)N_ * 4);
    float*        ssum = (float*)oalloc((size_t)N_ * 4);

    // ---- d_ws: rst (51.2MB) + WT (0.5MB) ----
    char* wsb = (char*)d_ws;
    size_t off = 0;
    auto alloc = [&](size_t nbytes) {
        void* p = wsb + off;
        off += (nbytes + 255) & ~(size_t)255;
        return p;
    };
    float* rst = (float*)alloc((size_t)N_ * D * 4);
    float* WT  = (float*)alloc(256 * 512 * 4);
    (void)ws_size;

    const int featBlocks = (N_ + FT - 1) / FT;
    const int elerBlocks = (N_ * 64 + 255) / 256;
    const int edgeBlocks = (E_ + 255) / 256;
    const int e3Blocks   = (int)(((size_t)E_ * 64 + 255) / 256);
    const int lstmBlocks = (N_ + LT - 1) / LT;

    wprep_kernel<<<512, 256, 0, stream>>>(W_ih, W_hh, WT);

    const int* srcs[2] = {src0, src1};
    const int* dsts[2] = {dst0, dst1};
    const float* layer_in = x;
    for (int L = 0; L < 2; ++L) {
        feat_kernel<<<featBlocks, 256, 0, stream>>>(layer_in, W, feat, N_);
        eler_kernel<<<elerBlocks, 256, 0, stream>>>(feat, attn_l, attn_r, el, er, N_);
        init_kernel<<<2048, 256, 0, stream>>>(rst, mkey, ssum, N_);
        edge1_kernel<<<edgeBlocks, 256, 0, stream>>>(srcs[L], dsts[L], el, er, ebuf, mkey, E_);
        edge2_kernel<<<edgeBlocks, 256, 0, stream>>>(dsts[L], ebuf, mkey, ssum, E_);
        edge3_kernel<<<e3Blocks, 256, 0, stream>>>(srcs[L], dsts[L], ebuf, ssum, feat, rst, E_);
        bias_kernel<<<2048, 256, 0, stream>>>(rst, gbias, N_ * D);
        layer_in = rst;  // x1 / x2 live in rst
    }

    lstm_kernel<<<lstmBlocks, 256, 0, stream>>>(rst, h, c, WT, b_ih, b_hh, out, N_);
}

// Round 6
// 1341.933 us; speedup vs baseline: 1.7540x; 1.7540x over previous
//
#include <hip/hip_runtime.h>

// GeniePath: 2x GAT(H=1,D=128) + LSTM step. N=100000, E=1600000, D=OUT=128.
// Inputs f32, output f32: [h1 (N*128)] [h1 (N*128)] [c1 (N*128)]
//
// Round 5->6: replace atomic edge scatter (800MB writes/layer) with CSR
// build + wave-per-node gather aggregation (51MB writes/layer, no atomics
// in the hot loop, softmax fused).
//
// d_ws (51.7MB): rst f32 + WT f32. d_out (153.6MB) holds transients:
// feat (51.2MB), el/er, rowptr0/1, csrc0/1 (6.4MB ea), cnt, cur, bsum.
// All transients dead before lstm_kernel rewrites every output element.

#define D 128
#define NEG_SLOPE 0.2f
#define SCAN_E 1024

// ---------------- feat = x @ W  (W f32 [128][128] row-major) ----------------
#define FT 16
__global__ __launch_bounds__(256) void feat_kernel(const float* __restrict__ xin,
                                                   const float* __restrict__ W,
                                                   float* __restrict__ feat, int N_) {
    __shared__ float xt[FT][D];
    int bn = blockIdx.x * FT;
    int tid = threadIdx.x;
    for (int idx = tid; idx < FT * (D / 4); idx += 256) {
        int n = idx >> 5, q = idx & 31;
        int gn = bn + n;
        float4 v = make_float4(0.f, 0.f, 0.f, 0.f);
        if (gn < N_) v = ((const float4*)(xin + (size_t)gn * D))[q];
        ((float4*)xt[n])[q] = v;
    }
    __syncthreads();
    int j = tid & 127;
    int h = tid >> 7;  // 0 or 1
    float acc[8];
#pragma unroll
    for (int p = 0; p < 8; ++p) acc[p] = 0.f;
    for (int k = 0; k < D; k += 4) {
        float w0 = W[(k + 0) * D + j];
        float w1 = W[(k + 1) * D + j];
        float w2 = W[(k + 2) * D + j];
        float w3 = W[(k + 3) * D + j];
#pragma unroll
        for (int p = 0; p < 8; ++p) {
            int n = h + 2 * p;
            float4 xv = *(const float4*)&xt[n][k];
            acc[p] += xv.x * w0 + xv.y * w1 + xv.z * w2 + xv.w * w3;
        }
    }
#pragma unroll
    for (int p = 0; p < 8; ++p) {
        int n = h + 2 * p;
        int gn = bn + n;
        if (gn < N_) feat[(size_t)gn * D + j] = acc[p];
    }
}

// ---------------- el/er: one wave per node ----------------
__global__ __launch_bounds__(256) void eler_kernel(const float* __restrict__ feat,
                                                   const float* __restrict__ al,
                                                   const float* __restrict__ ar,
                                                   float* __restrict__ el,
                                                   float* __restrict__ er, int N_) {
    int gw = (int)((blockIdx.x * 256 + threadIdx.x) >> 6);
    int lane = threadIdx.x & 63;
    if (gw >= N_) return;
    const float* f = feat + (size_t)gw * D;
    float a = f[lane], b = f[lane + 64];
    float pl = a * al[lane] + b * al[lane + 64];
    float pr = a * ar[lane] + b * ar[lane + 64];
#pragma unroll
    for (int m = 32; m; m >>= 1) {
        pl += __shfl_xor(pl, m);
        pr += __shfl_xor(pr, m);
    }
    if (lane == 0) { el[gw] = pl; er[gw] = pr; }
}

// ---------------- CSR build ----------------
__global__ void zero_kernel(int* __restrict__ p, int n) {
    int i = blockIdx.x * 256 + threadIdx.x;
    if (i < n) p[i] = 0;
}

__global__ void hist_kernel(const int* __restrict__ dst, int* __restrict__ cnt, int E_) {
    int i = blockIdx.x * 256 + threadIdx.x;
    if (i < E_) atomicAdd(cnt + dst[i], 1);
}

// inclusive scan, stage 1: per-block (1024 elems), writes partials to rp1[i]=rowptr[i+1]
__global__ __launch_bounds__(256) void scan1_kernel(const int* __restrict__ cnt,
                                                    int* __restrict__ rp1,
                                                    int* __restrict__ bsum, int n) {
    __shared__ int ls[256];
    int b = blockIdx.x, t = threadIdx.x;
    int i0 = b * SCAN_E + t * 4;
    int v0 = (i0 + 0 < n) ? cnt[i0 + 0] : 0;
    int v1 = (i0 + 1 < n) ? cnt[i0 + 1] : 0;
    int v2 = (i0 + 2 < n) ? cnt[i0 + 2] : 0;
    int v3 = (i0 + 3 < n) ? cnt[i0 + 3] : 0;
    int s0 = v0, s1 = s0 + v1, s2 = s1 + v2, s3 = s2 + v3;
    ls[t] = s3;
    __syncthreads();
    for (int off = 1; off < 256; off <<= 1) {
        int x = (t >= off) ? ls[t - off] : 0;
        __syncthreads();
        ls[t] += x;
        __syncthreads();
    }
    int excl = ls[t] - s3;
    if (i0 + 0 < n) rp1[i0 + 0] = s0 + excl;
    if (i0 + 1 < n) rp1[i0 + 1] = s1 + excl;
    if (i0 + 2 < n) rp1[i0 + 2] = s2 + excl;
    if (i0 + 3 < n) rp1[i0 + 3] = s3 + excl;
    if (t == 255) bsum[b] = ls[255];
}

// stage 2: single block, inclusive scan of block sums (nb <= 1024)
__global__ __launch_bounds__(256) void scan2_kernel(int* __restrict__ bsum, int nb) {
    __shared__ int ls[256];
    int t = threadIdx.x;
    int i0 = t * 4;
    int v0 = (i0 + 0 < nb) ? bsum[i0 + 0] : 0;
    int v1 = (i0 + 1 < nb) ? bsum[i0 + 1] : 0;
    int v2 = (i0 + 2 < nb) ? bsum[i0 + 2] : 0;
    int v3 = (i0 + 3 < nb) ? bsum[i0 + 3] : 0;
    int s0 = v0, s1 = s0 + v1, s2 = s1 + v2, s3 = s2 + v3;
    ls[t] = s3;
    __syncthreads();
    for (int off = 1; off < 256; off <<= 1) {
        int x = (t >= off) ? ls[t - off] : 0;
        __syncthreads();
        ls[t] += x;
        __syncthreads();
    }
    int excl = ls[t] - s3;
    if (i0 + 0 < nb) bsum[i0 + 0] = s0 + excl;
    if (i0 + 1 < nb) bsum[i0 + 1] = s1 + excl;
    if (i0 + 2 < nb) bsum[i0 + 2] = s2 + excl;
    if (i0 + 3 < nb) bsum[i0 + 3] = s3 + excl;
}

// stage 3: add block offsets into rowptr[i+1]; set rowptr[0]=0
__global__ void scan3_kernel(int* __restrict__ rowptr, const int* __restrict__ bsum, int n) {
    int i = blockIdx.x * 256 + threadIdx.x;
    if (i < n) {
        int b = i / SCAN_E;
        if (b > 0) rowptr[i + 1] += bsum[b - 1];
    }
    if (i == 0) rowptr[0] = 0;
}

__global__ void curcopy_kernel(const int* __restrict__ rowptr, int* __restrict__ cur, int n) {
    int i = blockIdx.x * 256 + threadIdx.x;
    if (i < n) cur[i] = rowptr[i];
}

__global__ void scatter_kernel(const int* __restrict__ src, const int* __restrict__ dst,
                               int* __restrict__ cur, int* __restrict__ csrc, int E_) {
    int i = blockIdx.x * 256 + threadIdx.x;
    if (i >= E_) return;
    int d = dst[i];
    int pos = atomicAdd(cur + d, 1);
    csrc[pos] = src[i];
}

// ---------------- fused softmax + aggregation: one wave per dst node ----------------
__global__ __launch_bounds__(256) void agg_kernel(const int* __restrict__ csrc,
                                                  const int* __restrict__ rowptr,
                                                  const float* __restrict__ el,
                                                  const float* __restrict__ er,
                                                  const float* __restrict__ feat,
                                                  const float* __restrict__ bias,
                                                  float* __restrict__ rst, int N_) {
    int gw = blockIdx.x * 4 + (threadIdx.x >> 6);
    int lane = threadIdx.x & 63;
    if (gw >= N_) return;
    int r0 = rowptr[gw], r1 = rowptr[gw + 1];
    float erd = er[gw];
    // pass A: segment max
    float m = -3.4e38f;
    for (int base = r0; base < r1; base += 64) {
        int i = base + lane;
        float ev = -3.4e38f;
        if (i < r1) {
            int s = csrc[i];
            float v = el[s] + erd;
            ev = v > 0.f ? v : NEG_SLOPE * v;
        }
#pragma unroll
        for (int off = 32; off; off >>= 1) ev = fmaxf(ev, __shfl_xor(ev, off));
        m = fmaxf(m, ev);
    }
    // pass B: exp, sum, weighted feat accumulation (2 cols per lane)
    float acc0 = 0.f, acc1 = 0.f, lsum = 0.f;
    for (int base = r0; base < r1; base += 64) {
        int i = base + lane;
        float ex = 0.f;
        int s = 0;
        if (i < r1) {
            s = csrc[i];
            float v = el[s] + erd;
            v = v > 0.f ? v : NEG_SLOPE * v;
            ex = expf(v - m);
        }
        lsum += ex;
        int cntc = min(64, r1 - base);
        for (int j = 0; j < cntc; ++j) {
            float exj = __shfl(ex, j);
            int sj = __shfl(s, j);
            const float* f = feat + (size_t)sj * D;
            acc0 += f[lane] * exj;
            acc1 += f[lane + 64] * exj;
        }
    }
#pragma unroll
    for (int off = 32; off; off >>= 1) lsum += __shfl_xor(lsum, off);
    float inv = (r1 > r0) ? 1.f / lsum : 0.f;
    rst[(size_t)gw * D + lane]      = acc0 * inv + bias[lane];
    rst[(size_t)gw * D + lane + 64] = acc1 * inv + bias[lane + 64];
}

// ---------------- LSTM weight transpose: WT[k][j] = Wcat[j][k] ----------------
__global__ void wprep_kernel(const float* __restrict__ W_ih, const float* __restrict__ W_hh,
                             float* __restrict__ WT) {
    int idx = blockIdx.x * 256 + threadIdx.x;  // 256*512 elements
    if (idx >= 256 * 512) return;
    int j = idx & 511, k = idx >> 9;
    float v = (k < 128) ? W_ih[j * 128 + k] : W_hh[j * 128 + (k - 128)];
    WT[k * 512 + j] = v;
}

// ---------------- fused LSTM (all f32), writes f32 outputs ----------------
#define LT 16
__global__ __launch_bounds__(256) void lstm_kernel(const float* __restrict__ x2,
                                                   const float* __restrict__ h0,
                                                   const float* __restrict__ c0,
                                                   const float* __restrict__ WT,
                                                   const float* __restrict__ b_ih,
                                                   const float* __restrict__ b_hh,
                                                   float* __restrict__ out, int N_) {
    __shared__ float xh[LT][256];
    __shared__ float gbuf[LT][512];
    int bn = blockIdx.x * LT;
    int tid = threadIdx.x;
    for (int idx = tid; idx < LT * 64; idx += 256) {
        int n = idx >> 6, q = idx & 63;
        int gn = bn + n;
        float4 v = make_float4(0.f, 0.f, 0.f, 0.f);
        if (gn < N_) {
            if (q < 32) v = ((const float4*)(x2 + (size_t)gn * D))[q];
            else        v = ((const float4*)(h0 + (size_t)gn * D))[q - 32];
        }
        ((float4*)xh[n])[q] = v;
    }
    __syncthreads();
    float acc0[LT], acc1[LT];
#pragma unroll
    for (int n = 0; n < LT; ++n) { acc0[n] = 0.f; acc1[n] = 0.f; }
    for (int k = 0; k < 256; k += 4) {
        float w00 = WT[(k + 0) * 512 + tid];
        float w01 = WT[(k + 1) * 512 + tid];
        float w02 = WT[(k + 2) * 512 + tid];
        float w03 = WT[(k + 3) * 512 + tid];
        float w10 = WT[(k + 0) * 512 + tid + 256];
        float w11 = WT[(k + 1) * 512 + tid + 256];
        float w12 = WT[(k + 2) * 512 + tid + 256];
        float w13 = WT[(k + 3) * 512 + tid + 256];
#pragma unroll
        for (int n = 0; n < LT; ++n) {
            float4 xv = *(const float4*)&xh[n][k];
            acc0[n] += xv.x * w00 + xv.y * w01 + xv.z * w02 + xv.w * w03;
            acc1[n] += xv.x * w10 + xv.y * w11 + xv.z * w12 + xv.w * w13;
        }
    }
    float bs0 = b_ih[tid] + b_hh[tid];
    float bs1 = b_ih[tid + 256] + b_hh[tid + 256];
#pragma unroll
    for (int n = 0; n < LT; ++n) {
        gbuf[n][tid] = acc0[n] + bs0;
        gbuf[n][tid + 256] = acc1[n] + bs1;
    }
    __syncthreads();
    size_t NO = (size_t)N_ * D;
    for (int idx = tid; idx < LT * D; idx += 256) {
        int n = idx >> 7, dd = idx & 127;
        int gn = bn + n;
        if (gn >= N_) continue;
        float iv = gbuf[n][dd];
        float fv = gbuf[n][128 + dd];
        float gv = gbuf[n][256 + dd];
        float ov = gbuf[n][384 + dd];
        float c0v = c0[(size_t)gn * D + dd];
        float ig = 1.f / (1.f + expf(-iv));
        float fg = 1.f / (1.f + expf(-fv));
        float og = 1.f / (1.f + expf(-ov));
        float gg = tanhf(gv);
        float c1 = fg * c0v + ig * gg;
        float h1 = og * tanhf(c1);
        size_t o = (size_t)gn * D + dd;
        out[o] = h1;
        out[NO + o] = h1;
        out[2 * NO + o] = c1;
    }
}

extern "C" void kernel_launch(void* const* d_in, const int* in_sizes, int n_in,
                              void* d_out, int out_size, void* d_ws, size_t ws_size,
                              hipStream_t stream) {
    const float* x      = (const float*)d_in[0];
    const float* h      = (const float*)d_in[1];
    const float* c      = (const float*)d_in[2];
    const int*   src0   = (const int*)d_in[3];
    const int*   dst0   = (const int*)d_in[4];
    const int*   src1   = (const int*)d_in[5];
    const int*   dst1   = (const int*)d_in[6];
    const float* W      = (const float*)d_in[7];
    const float* attn_l = (const float*)d_in[8];
    const float* attn_r = (const float*)d_in[9];
    const float* gbias  = (const float*)d_in[10];
    const float* W_ih   = (const float*)d_in[11];
    const float* W_hh   = (const float*)d_in[12];
    const float* b_ih   = (const float*)d_in[13];
    const float* b_hh   = (const float*)d_in[14];
    float* out = (float*)d_out;

    const int N_ = in_sizes[1] / D;  // h is (1,N,128)
    const int E_ = in_sizes[3];
    const int nb = (N_ + SCAN_E - 1) / SCAN_E;  // scan blocks (98 for N=100k)

    // ---- transients carved out of d_out (3*N*D*4 = 153.6MB) ----
    char* ob = (char*)d_out;
    size_t ooff = 0;
    auto oalloc = [&](size_t nbytes) {
        void* p = ob + ooff;
        ooff += (nbytes + 255) & ~(size_t)255;
        return p;
    };
    float* feat = (float*)oalloc((size_t)N_ * D * 4);  // 51.2MB
    float* el   = (float*)oalloc((size_t)N_ * 4);
    float* er   = (float*)oalloc((size_t)N_ * 4);
    int*   rp0  = (int*)oalloc((size_t)(N_ + 1) * 4);
    int*   rp1  = (int*)oalloc((size_t)(N_ + 1) * 4);
    int*   cs0  = (int*)oalloc((size_t)E_ * 4);        // 6.4MB
    int*   cs1  = (int*)oalloc((size_t)E_ * 4);        // 6.4MB
    int*   cnt  = (int*)oalloc((size_t)N_ * 4);
    int*   cur  = (int*)oalloc((size_t)N_ * 4);
    int*   bsum = (int*)oalloc((size_t)1024 * 4);

    // ---- d_ws: rst (51.2MB) + WT (0.5MB) ----
    char* wsb = (char*)d_ws;
    size_t off = 0;
    auto alloc = [&](size_t nbytes) {
        void* p = wsb + off;
        off += (nbytes + 255) & ~(size_t)255;
        return p;
    };
    float* rst = (float*)alloc((size_t)N_ * D * 4);
    float* WT  = (float*)alloc(256 * 512 * 4);
    (void)ws_size;

    const int featBlocks = (N_ + FT - 1) / FT;
    const int elerBlocks = (N_ * 64 + 255) / 256;
    const int edgeBlocks = (E_ + 255) / 256;
    const int nodeBlocks = (N_ + 255) / 256;
    const int aggBlocks  = (N_ + 3) / 4;
    const int lstmBlocks = (N_ + LT - 1) / LT;

    wprep_kernel<<<512, 256, 0, stream>>>(W_ih, W_hh, WT);

    // ---- build CSR for both graphs ----
    const int* srcs[2] = {src0, src1};
    const int* dsts[2] = {dst0, dst1};
    int* rps[2] = {rp0, rp1};
    int* css[2] = {cs0, cs1};
    for (int g = 0; g < 2; ++g) {
        zero_kernel<<<nodeBlocks, 256, 0, stream>>>(cnt, N_);
        hist_kernel<<<edgeBlocks, 256, 0, stream>>>(dsts[g], cnt, E_);
        scan1_kernel<<<nb, 256, 0, stream>>>(cnt, rps[g] + 1, bsum, N_);
        scan2_kernel<<<1, 256, 0, stream>>>(bsum, nb);
        scan3_kernel<<<nodeBlocks, 256, 0, stream>>>(rps[g], bsum, N_);
        curcopy_kernel<<<nodeBlocks, 256, 0, stream>>>(rps[g], cur, N_);
        scatter_kernel<<<edgeBlocks, 256, 0, stream>>>(srcs[g], dsts[g], cur, css[g], E_);
    }

    // ---- two GAT layers ----
    const float* layer_in = x;
    for (int L = 0; L < 2; ++L) {
        feat_kernel<<<featBlocks, 256, 0, stream>>>(layer_in, W, feat, N_);
        eler_kernel<<<elerBlocks, 256, 0, stream>>>(feat, attn_l, attn_r, el, er, N_);
        agg_kernel<<<aggBlocks, 256, 0, stream>>>(css[L], rps[L], el, er, feat, gbias, rst, N_);
        layer_in = rst;  // x1 / x2 live in rst
    }

    lstm_kernel<<<lstmBlocks, 256, 0, stream>>>(rst, h, c, WT, b_ih, b_hh, out, N_);
}

// Round 7
// 930.817 us; speedup vs baseline: 2.5287x; 1.4417x over previous
//
#include <hip/hip_runtime.h>

// GeniePath: 2x GAT(H=1,D=128) + LSTM step. N=100000, E=1600000, D=OUT=128.
// Inputs f32, output f32: [h1 (N*128)] [h1 (N*128)] [c1 (N*128)]
//
// Round 6->7: feat GEMM and LSTM gate GEMM moved to bf16 MFMA
// (v_mfma_f32_16x16x32_bf16, f32 accum). Weights pre-swizzled into
// B-fragment order; LSTM epilogue fully in registers (wave owns a 32-col
// slice of all 4 gates).
//
// d_ws: rst f32 (51.2MB) + WTb bf16-swizzled (256KB) + Wswz bf16 (32KB).
// d_out (153.6MB) holds transients (feat, el/er, CSR) - all dead before
// the LSTM kernel rewrites every output element.

#define D 128
#define NEG_SLOPE 0.2f
#define SCAN_E 1024

typedef short bf16x8 __attribute__((ext_vector_type(8)));
typedef float f32x4 __attribute__((ext_vector_type(4)));

__device__ __forceinline__ unsigned short f2bf(float x) {
    unsigned int b = __float_as_uint(x);
    b += 0x7fff + ((b >> 16) & 1);
    return (unsigned short)(b >> 16);
}

// ---------------- weight swizzle: feat W -> B-fragment order ----------------
// Wswz[((ct*4+ks)*64+lane)*8+i] = bf16(W[k][col]), col=ct*16+(lane&15),
// k=ks*32+(lane>>4)*8+i.  (8 ct, 4 ks)
__global__ void wprep_feat_kernel(const float* __restrict__ W,
                                  unsigned short* __restrict__ Wswz) {
    int t = blockIdx.x * 256 + threadIdx.x;  // 2048 threads
    if (t >= 8 * 4 * 64) return;
    int ct = t >> 8, ks = (t >> 6) & 3, lane = t & 63;
    int col = ct * 16 + (lane & 15);
    int k0 = ks * 32 + ((lane >> 4) << 3);
#pragma unroll
    for (int i = 0; i < 8; ++i)
        Wswz[(size_t)t * 8 + i] = f2bf(W[(k0 + i) * D + col]);
}

// ---------------- weight swizzle: LSTM Wcat -> B-fragment order ----------------
// Wcat[j][k] = k<128 ? W_ih[j][k] : W_hh[j][k-128]   (j=0..511, k=0..255)
// WTb[((ct*8+ks)*64+lane)*8+i] = bf16(Wcat[col][k]), col=ct*16+(lane&15),
// k=ks*32+(lane>>4)*8+i.  (32 ct, 8 ks)
__global__ void wprep_lstm_kernel(const float* __restrict__ W_ih,
                                  const float* __restrict__ W_hh,
                                  unsigned short* __restrict__ WTb) {
    int t = blockIdx.x * 256 + threadIdx.x;  // 16384 threads
    if (t >= 32 * 8 * 64) return;
    int ct = t >> 9, ks = (t >> 6) & 7, lane = t & 63;
    int col = ct * 16 + (lane & 15);
    int k0 = ks * 32 + ((lane >> 4) << 3);
#pragma unroll
    for (int i = 0; i < 8; ++i) {
        int k = k0 + i;
        float v = (k < 128) ? W_ih[col * 128 + k] : W_hh[col * 128 + (k - 128)];
        WTb[(size_t)t * 8 + i] = f2bf(v);
    }
}

// ---------------- feat = x @ W via MFMA (M=32/block, 4 waves) ----------------
#define FM 32
__global__ __launch_bounds__(256) void feat_mfma_kernel(const float* __restrict__ xin,
                                                        const unsigned short* __restrict__ Wswz,
                                                        float* __restrict__ feat, int N_) {
    __shared__ unsigned short xb[FM][136];  // row stride 272B (16B-aligned), 2-way banks
    int tid = threadIdx.x;
    int bn = blockIdx.x * FM;
    for (int idx = tid; idx < FM * 16; idx += 256) {  // 8-elem chunks
        int n = idx >> 4, q = idx & 15;
        int gn = bn + n;
        unsigned short u[8];
        if (gn < N_) {
            const float* sp = xin + (size_t)gn * D + q * 8;
            float4 a = ((const float4*)sp)[0];
            float4 b = ((const float4*)sp)[1];
            u[0] = f2bf(a.x); u[1] = f2bf(a.y); u[2] = f2bf(a.z); u[3] = f2bf(a.w);
            u[4] = f2bf(b.x); u[5] = f2bf(b.y); u[6] = f2bf(b.z); u[7] = f2bf(b.w);
        } else {
#pragma unroll
            for (int i = 0; i < 8; ++i) u[i] = 0;
        }
#pragma unroll
        for (int i = 0; i < 8; ++i) xb[n][q * 8 + i] = u[i];
    }
    __syncthreads();
    int w = tid >> 6, l = tid & 63;
    f32x4 acc[2][2];
#pragma unroll
    for (int m = 0; m < 2; ++m)
#pragma unroll
        for (int p = 0; p < 2; ++p) acc[m][p] = (f32x4)0.f;
    int ar = l & 15, ak = (l >> 4) << 3;
#pragma unroll
    for (int ks = 0; ks < 4; ++ks) {
        bf16x8 a0 = *(const bf16x8*)&xb[ar][ks * 32 + ak];
        bf16x8 a1 = *(const bf16x8*)&xb[16 + ar][ks * 32 + ak];
#pragma unroll
        for (int p = 0; p < 2; ++p) {
            int ct = w * 2 + p;
            bf16x8 b = *(const bf16x8*)(Wswz + ((size_t)(ct * 4 + ks) * 64 + l) * 8);
            acc[0][p] = __builtin_amdgcn_mfma_f32_16x16x32_bf16(a0, b, acc[0][p], 0, 0, 0);
            acc[1][p] = __builtin_amdgcn_mfma_f32_16x16x32_bf16(a1, b, acc[1][p], 0, 0, 0);
        }
    }
#pragma unroll
    for (int p = 0; p < 2; ++p) {
        int col = (w * 2 + p) * 16 + (l & 15);
#pragma unroll
        for (int m = 0; m < 2; ++m)
#pragma unroll
            for (int r = 0; r < 4; ++r) {
                int gn = bn + m * 16 + ((l >> 4) << 2) + r;
                if (gn < N_) feat[(size_t)gn * D + col] = acc[m][p][r];
            }
    }
}

// ---------------- el/er: one wave per node ----------------
__global__ __launch_bounds__(256) void eler_kernel(const float* __restrict__ feat,
                                                   const float* __restrict__ al,
                                                   const float* __restrict__ ar,
                                                   float* __restrict__ el,
                                                   float* __restrict__ er, int N_) {
    int gw = (int)((blockIdx.x * 256 + threadIdx.x) >> 6);
    int lane = threadIdx.x & 63;
    if (gw >= N_) return;
    const float* f = feat + (size_t)gw * D;
    float a = f[lane], b = f[lane + 64];
    float pl = a * al[lane] + b * al[lane + 64];
    float pr = a * ar[lane] + b * ar[lane + 64];
#pragma unroll
    for (int m = 32; m; m >>= 1) {
        pl += __shfl_xor(pl, m);
        pr += __shfl_xor(pr, m);
    }
    if (lane == 0) { el[gw] = pl; er[gw] = pr; }
}

// ---------------- CSR build ----------------
__global__ void zero_kernel(int* __restrict__ p, int n) {
    int i = blockIdx.x * 256 + threadIdx.x;
    if (i < n) p[i] = 0;
}

__global__ void hist_kernel(const int* __restrict__ dst, int* __restrict__ cnt, int E_) {
    int i = blockIdx.x * 256 + threadIdx.x;
    if (i < E_) atomicAdd(cnt + dst[i], 1);
}

__global__ __launch_bounds__(256) void scan1_kernel(const int* __restrict__ cnt,
                                                    int* __restrict__ rp1,
                                                    int* __restrict__ bsum, int n) {
    __shared__ int ls[256];
    int b = blockIdx.x, t = threadIdx.x;
    int i0 = b * SCAN_E + t * 4;
    int v0 = (i0 + 0 < n) ? cnt[i0 + 0] : 0;
    int v1 = (i0 + 1 < n) ? cnt[i0 + 1] : 0;
    int v2 = (i0 + 2 < n) ? cnt[i0 + 2] : 0;
    int v3 = (i0 + 3 < n) ? cnt[i0 + 3] : 0;
    int s0 = v0, s1 = s0 + v1, s2 = s1 + v2, s3 = s2 + v3;
    ls[t] = s3;
    __syncthreads();
    for (int off = 1; off < 256; off <<= 1) {
        int x = (t >= off) ? ls[t - off] : 0;
        __syncthreads();
        ls[t] += x;
        __syncthreads();
    }
    int excl = ls[t] - s3;
    if (i0 + 0 < n) rp1[i0 + 0] = s0 + excl;
    if (i0 + 1 < n) rp1[i0 + 1] = s1 + excl;
    if (i0 + 2 < n) rp1[i0 + 2] = s2 + excl;
    if (i0 + 3 < n) rp1[i0 + 3] = s3 + excl;
    if (t == 255) bsum[b] = ls[255];
}

__global__ __launch_bounds__(256) void scan2_kernel(int* __restrict__ bsum, int nb) {
    __shared__ int ls[256];
    int t = threadIdx.x;
    int i0 = t * 4;
    int v0 = (i0 + 0 < nb) ? bsum[i0 + 0] : 0;
    int v1 = (i0 + 1 < nb) ? bsum[i0 + 1] : 0;
    int v2 = (i0 + 2 < nb) ? bsum[i0 + 2] : 0;
    int v3 = (i0 + 3 < nb) ? bsum[i0 + 3] : 0;
    int s0 = v0, s1 = s0 + v1, s2 = s1 + v2, s3 = s2 + v3;
    ls[t] = s3;
    __syncthreads();
    for (int off = 1; off < 256; off <<= 1) {
        int x = (t >= off) ? ls[t - off] : 0;
        __syncthreads();
        ls[t] += x;
        __syncthreads();
    }
    int excl = ls[t] - s3;
    if (i0 + 0 < nb) bsum[i0 + 0] = s0 + excl;
    if (i0 + 1 < nb) bsum[i0 + 1] = s1 + excl;
    if (i0 + 2 < nb) bsum[i0 + 2] = s2 + excl;
    if (i0 + 3 < nb) bsum[i0 + 3] = s3 + excl;
}

__global__ void scan3_kernel(int* __restrict__ rowptr, const int* __restrict__ bsum, int n) {
    int i = blockIdx.x * 256 + threadIdx.x;
    if (i < n) {
        int b = i / SCAN_E;
        if (b > 0) rowptr[i + 1] += bsum[b - 1];
    }
    if (i == 0) rowptr[0] = 0;
}

__global__ void curcopy_kernel(const int* __restrict__ rowptr, int* __restrict__ cur, int n) {
    int i = blockIdx.x * 256 + threadIdx.x;
    if (i < n) cur[i] = rowptr[i];
}

__global__ void scatter_kernel(const int* __restrict__ src, const int* __restrict__ dst,
                               int* __restrict__ cur, int* __restrict__ csrc, int E_) {
    int i = blockIdx.x * 256 + threadIdx.x;
    if (i >= E_) return;
    int d = dst[i];
    int pos = atomicAdd(cur + d, 1);
    csrc[pos] = src[i];
}

// ---------------- fused softmax + aggregation: one wave per dst node ----------------
__global__ __launch_bounds__(256) void agg_kernel(const int* __restrict__ csrc,
                                                  const int* __restrict__ rowptr,
                                                  const float* __restrict__ el,
                                                  const float* __restrict__ er,
                                                  const float* __restrict__ feat,
                                                  const float* __restrict__ bias,
                                                  float* __restrict__ rst, int N_) {
    int gw = blockIdx.x * 4 + (threadIdx.x >> 6);
    int lane = threadIdx.x & 63;
    if (gw >= N_) return;
    int r0 = rowptr[gw], r1 = rowptr[gw + 1];
    float erd = er[gw];
    float m = -3.4e38f;
    for (int base = r0; base < r1; base += 64) {
        int i = base + lane;
        float ev = -3.4e38f;
        if (i < r1) {
            int s = csrc[i];
            float v = el[s] + erd;
            ev = v > 0.f ? v : NEG_SLOPE * v;
        }
#pragma unroll
        for (int off = 32; off; off >>= 1) ev = fmaxf(ev, __shfl_xor(ev, off));
        m = fmaxf(m, ev);
    }
    float acc0 = 0.f, acc1 = 0.f, lsum = 0.f;
    for (int base = r0; base < r1; base += 64) {
        int i = base + lane;
        float ex = 0.f;
        int s = 0;
        if (i < r1) {
            s = csrc[i];
            float v = el[s] + erd;
            v = v > 0.f ? v : NEG_SLOPE * v;
            ex = expf(v - m);
        }
        lsum += ex;
        int cntc = min(64, r1 - base);
        for (int j = 0; j < cntc; ++j) {
            float exj = __shfl(ex, j);
            int sj = __shfl(s, j);
            const float* f = feat + (size_t)sj * D;
            acc0 += f[lane] * exj;
            acc1 += f[lane + 64] * exj;
        }
    }
#pragma unroll
    for (int off = 32; off; off >>= 1) lsum += __shfl_xor(lsum, off);
    float inv = (r1 > r0) ? 1.f / lsum : 0.f;
    rst[(size_t)gw * D + lane]      = acc0 * inv + bias[lane];
    rst[(size_t)gw * D + lane + 64] = acc1 * inv + bias[lane + 64];
}

// ---------------- LSTM via MFMA (M=32/block, 4 waves, reg epilogue) ----------------
#define LM 32
__global__ __launch_bounds__(256) void lstm_mfma_kernel(const float* __restrict__ x2,
                                                        const float* __restrict__ h0,
                                                        const float* __restrict__ c0,
                                                        const unsigned short* __restrict__ WTb,
                                                        const float* __restrict__ b_ih,
                                                        const float* __restrict__ b_hh,
                                                        float* __restrict__ out, int N_) {
    __shared__ unsigned short xb[LM][264];  // row stride 528B (16B-aligned), 2-way banks
    int tid = threadIdx.x;
    int bn = blockIdx.x * LM;
    // A-tile: [x2 | h0] 32 nodes x 256 k -> bf16 LDS
    for (int idx = tid; idx < LM * 32; idx += 256) {  // 8-elem chunks
        int n = idx >> 5, q = idx & 31;
        int gn = bn + n;
        unsigned short u[8];
        if (gn < N_) {
            const float* sp = (q < 16) ? (x2 + (size_t)gn * D + q * 8)
                                       : (h0 + (size_t)gn * D + (q - 16) * 8);
            float4 a = ((const float4*)sp)[0];
            float4 b = ((const float4*)sp)[1];
            u[0] = f2bf(a.x); u[1] = f2bf(a.y); u[2] = f2bf(a.z); u[3] = f2bf(a.w);
            u[4] = f2bf(b.x); u[5] = f2bf(b.y); u[6] = f2bf(b.z); u[7] = f2bf(b.w);
        } else {
#pragma unroll
            for (int i = 0; i < 8; ++i) u[i] = 0;
        }
#pragma unroll
        for (int i = 0; i < 8; ++i) xb[n][q * 8 + i] = u[i];
    }
    __syncthreads();
    int w = tid >> 6, l = tid & 63;
    // wave w covers cols [w*32, w*32+32) of each gate; ct = g4*8 + w*2 + p
    f32x4 acc[2][4][2];
#pragma unroll
    for (int m = 0; m < 2; ++m)
#pragma unroll
        for (int g4 = 0; g4 < 4; ++g4)
#pragma unroll
            for (int p = 0; p < 2; ++p) acc[m][g4][p] = (f32x4)0.f;
    int ar = l & 15, ak = (l >> 4) << 3;
#pragma unroll
    for (int ks = 0; ks < 8; ++ks) {
        bf16x8 a0 = *(const bf16x8*)&xb[ar][ks * 32 + ak];
        bf16x8 a1 = *(const bf16x8*)&xb[16 + ar][ks * 32 + ak];
#pragma unroll
        for (int g4 = 0; g4 < 4; ++g4)
#pragma unroll
            for (int p = 0; p < 2; ++p) {
                int ct = g4 * 8 + w * 2 + p;
                bf16x8 b = *(const bf16x8*)(WTb + ((size_t)(ct * 8 + ks) * 64 + l) * 8);
                acc[0][g4][p] = __builtin_amdgcn_mfma_f32_16x16x32_bf16(a0, b, acc[0][g4][p], 0, 0, 0);
                acc[1][g4][p] = __builtin_amdgcn_mfma_f32_16x16x32_bf16(a1, b, acc[1][g4][p], 0, 0, 0);
            }
    }
    size_t NO = (size_t)N_ * D;
#pragma unroll
    for (int p = 0; p < 2; ++p) {
        int col = w * 32 + p * 16 + (l & 15);
        float bi = b_ih[col]       + b_hh[col];
        float bf_ = b_ih[128 + col] + b_hh[128 + col];
        float bg = b_ih[256 + col] + b_hh[256 + col];
        float bo = b_ih[384 + col] + b_hh[384 + col];
#pragma unroll
        for (int m = 0; m < 2; ++m)
#pragma unroll
            for (int r = 0; r < 4; ++r) {
                int gn = bn + m * 16 + ((l >> 4) << 2) + r;
                if (gn >= N_) continue;
                float iv = acc[m][0][p][r] + bi;
                float fv = acc[m][1][p][r] + bf_;
                float gv = acc[m][2][p][r] + bg;
                float ov = acc[m][3][p][r] + bo;
                float c0v = c0[(size_t)gn * D + col];
                float ig = 1.f / (1.f + expf(-iv));
                float fg = 1.f / (1.f + expf(-fv));
                float og = 1.f / (1.f + expf(-ov));
                float gg = tanhf(gv);
                float c1 = fg * c0v + ig * gg;
                float h1 = og * tanhf(c1);
                size_t o = (size_t)gn * D + col;
                out[o] = h1;
                out[NO + o] = h1;
                out[2 * NO + o] = c1;
            }
    }
}

extern "C" void kernel_launch(void* const* d_in, const int* in_sizes, int n_in,
                              void* d_out, int out_size, void* d_ws, size_t ws_size,
                              hipStream_t stream) {
    const float* x      = (const float*)d_in[0];
    const float* h      = (const float*)d_in[1];
    const float* c      = (const float*)d_in[2];
    const int*   src0   = (const int*)d_in[3];
    const int*   dst0   = (const int*)d_in[4];
    const int*   src1   = (const int*)d_in[5];
    const int*   dst1   = (const int*)d_in[6];
    const float* W      = (const float*)d_in[7];
    const float* attn_l = (const float*)d_in[8];
    const float* attn_r = (const float*)d_in[9];
    const float* gbias  = (const float*)d_in[10];
    const float* W_ih   = (const float*)d_in[11];
    const float* W_hh   = (const float*)d_in[12];
    const float* b_ih   = (const float*)d_in[13];
    const float* b_hh   = (const float*)d_in[14];
    float* out = (float*)d_out;

    const int N_ = in_sizes[1] / D;  // h is (1,N,128)
    const int E_ = in_sizes[3];
    const int nb = (N_ + SCAN_E - 1) / SCAN_E;

    // ---- transients carved out of d_out (3*N*D*4 = 153.6MB) ----
    char* ob = (char*)d_out;
    size_t ooff = 0;
    auto oalloc = [&](size_t nbytes) {
        void* p = ob + ooff;
        ooff += (nbytes + 255) & ~(size_t)255;
        return p;
    };
    float* feat = (float*)oalloc((size_t)N_ * D * 4);  // 51.2MB
    float* el   = (float*)oalloc((size_t)N_ * 4);
    float* er   = (float*)oalloc((size_t)N_ * 4);
    int*   rp0  = (int*)oalloc((size_t)(N_ + 1) * 4);
    int*   rp1  = (int*)oalloc((size_t)(N_ + 1) * 4);
    int*   cs0  = (int*)oalloc((size_t)E_ * 4);
    int*   cs1  = (int*)oalloc((size_t)E_ * 4);
    int*   cnt  = (int*)oalloc((size_t)N_ * 4);
    int*   cur  = (int*)oalloc((size_t)N_ * 4);
    int*   bsum = (int*)oalloc((size_t)1024 * 4);

    // ---- d_ws: rst + swizzled weights ----
    char* wsb = (char*)d_ws;
    size_t off = 0;
    auto alloc = [&](size_t nbytes) {
        void* p = wsb + off;
        off += (nbytes + 255) & ~(size_t)255;
        return p;
    };
    float*          rst  = (float*)alloc((size_t)N_ * D * 4);
    unsigned short* WTb  = (unsigned short*)alloc((size_t)32 * 8 * 64 * 8 * 2);  // 256KB
    unsigned short* Wswz = (unsigned short*)alloc((size_t)8 * 4 * 64 * 8 * 2);   // 32KB
    (void)ws_size;

    const int featBlocks = (N_ + FM - 1) / FM;
    const int elerBlocks = (N_ * 64 + 255) / 256;
    const int edgeBlocks = (E_ + 255) / 256;
    const int nodeBlocks = (N_ + 255) / 256;
    const int aggBlocks  = (N_ + 3) / 4;
    const int lstmBlocks = (N_ + LM - 1) / LM;

    wprep_feat_kernel<<<8, 256, 0, stream>>>(W, Wswz);
    wprep_lstm_kernel<<<64, 256, 0, stream>>>(W_ih, W_hh, WTb);

    // ---- build CSR for both graphs ----
    const int* srcs[2] = {src0, src1};
    const int* dsts[2] = {dst0, dst1};
    int* rps[2] = {rp0, rp1};
    int* css[2] = {cs0, cs1};
    for (int g = 0; g < 2; ++g) {
        zero_kernel<<<nodeBlocks, 256, 0, stream>>>(cnt, N_);
        hist_kernel<<<edgeBlocks, 256, 0, stream>>>(dsts[g], cnt, E_);
        scan1_kernel<<<nb, 256, 0, stream>>>(cnt, rps[g] + 1, bsum, N_);
        scan2_kernel<<<1, 256, 0, stream>>>(bsum, nb);
        scan3_kernel<<<nodeBlocks, 256, 0, stream>>>(rps[g], bsum, N_);
        curcopy_kernel<<<nodeBlocks, 256, 0, stream>>>(rps[g], cur, N_);
        scatter_kernel<<<edgeBlocks, 256, 0, stream>>>(srcs[g], dsts[g], cur, css[g], E_);
    }

    // ---- two GAT layers ----
    const float* layer_in = x;
    for (int L = 0; L < 2; ++L) {
        feat_mfma_kernel<<<featBlocks, 256, 0, stream>>>(layer_in, Wswz, feat, N_);
        eler_kernel<<<elerBlocks, 256, 0, stream>>>(feat, attn_l, attn_r, el, er, N_);
        agg_kernel<<<aggBlocks, 256, 0, stream>>>(css[L], rps[L], el, er, feat, gbias, rst, N_);
        layer_in = rst;
    }

    lstm_mfma_kernel<<<lstmBlocks, 256, 0, stream>>>(rst, h, c, WTb, b_ih, b_hh, out, N_);
}

// Round 8
// 881.407 us; speedup vs baseline: 2.6705x; 1.0561x over previous
//
#include <hip/hip_runtime.h>

// GeniePath: 2x GAT(H=1,D=128) + LSTM step. N=100000, E=1600000, D=OUT=128.
// Inputs f32, output f32: [h1 (N*128)] [h1 (N*128)] [c1 (N*128)]
//
// Round 7->8: lstm epilogue restructured. c0 staged to LDS coalesced;
// gate nonlinearities via __expf (fast path); h1/c1 transposed through LDS
// and stored as coalesced float4 (kills the 33% write amplification of the
// scattered 4B MFMA-layout stores).
//
// d_ws: rst f32 (51.2MB) + WTb bf16-swizzled (256KB) + Wswz bf16 (32KB).
// d_out (153.6MB) holds transients (feat, el/er, CSR) - all dead before
// the LSTM kernel rewrites every output element.

#define D 128
#define NEG_SLOPE 0.2f
#define SCAN_E 1024

typedef short bf16x8 __attribute__((ext_vector_type(8)));
typedef float f32x4 __attribute__((ext_vector_type(4)));

__device__ __forceinline__ unsigned short f2bf(float x) {
    unsigned int b = __float_as_uint(x);
    b += 0x7fff + ((b >> 16) & 1);
    return (unsigned short)(b >> 16);
}

__device__ __forceinline__ float fsig(float x) {
    return 1.f / (1.f + __expf(-x));
}
__device__ __forceinline__ float ftanh(float x) {
    x = fminf(15.f, fmaxf(-15.f, x));
    float t = __expf(2.f * x);
    return (t - 1.f) / (t + 1.f);
}

// ---------------- weight swizzle: feat W -> B-fragment order ----------------
__global__ void wprep_feat_kernel(const float* __restrict__ W,
                                  unsigned short* __restrict__ Wswz) {
    int t = blockIdx.x * 256 + threadIdx.x;
    if (t >= 8 * 4 * 64) return;
    int ct = t >> 8, ks = (t >> 6) & 3, lane = t & 63;
    int col = ct * 16 + (lane & 15);
    int k0 = ks * 32 + ((lane >> 4) << 3);
#pragma unroll
    for (int i = 0; i < 8; ++i)
        Wswz[(size_t)t * 8 + i] = f2bf(W[(k0 + i) * D + col]);
}

// ---------------- weight swizzle: LSTM Wcat -> B-fragment order ----------------
__global__ void wprep_lstm_kernel(const float* __restrict__ W_ih,
                                  const float* __restrict__ W_hh,
                                  unsigned short* __restrict__ WTb) {
    int t = blockIdx.x * 256 + threadIdx.x;
    if (t >= 32 * 8 * 64) return;
    int ct = t >> 9, ks = (t >> 6) & 7, lane = t & 63;
    int col = ct * 16 + (lane & 15);
    int k0 = ks * 32 + ((lane >> 4) << 3);
#pragma unroll
    for (int i = 0; i < 8; ++i) {
        int k = k0 + i;
        float v = (k < 128) ? W_ih[col * 128 + k] : W_hh[col * 128 + (k - 128)];
        WTb[(size_t)t * 8 + i] = f2bf(v);
    }
}

// ---------------- feat = x @ W via MFMA (M=32/block, 4 waves) ----------------
#define FM 32
__global__ __launch_bounds__(256) void feat_mfma_kernel(const float* __restrict__ xin,
                                                        const unsigned short* __restrict__ Wswz,
                                                        float* __restrict__ feat, int N_) {
    __shared__ unsigned short xb[FM][136];
    int tid = threadIdx.x;
    int bn = blockIdx.x * FM;
    for (int idx = tid; idx < FM * 16; idx += 256) {
        int n = idx >> 4, q = idx & 15;
        int gn = bn + n;
        unsigned short u[8];
        if (gn < N_) {
            const float* sp = xin + (size_t)gn * D + q * 8;
            float4 a = ((const float4*)sp)[0];
            float4 b = ((const float4*)sp)[1];
            u[0] = f2bf(a.x); u[1] = f2bf(a.y); u[2] = f2bf(a.z); u[3] = f2bf(a.w);
            u[4] = f2bf(b.x); u[5] = f2bf(b.y); u[6] = f2bf(b.z); u[7] = f2bf(b.w);
        } else {
#pragma unroll
            for (int i = 0; i < 8; ++i) u[i] = 0;
        }
#pragma unroll
        for (int i = 0; i < 8; ++i) xb[n][q * 8 + i] = u[i];
    }
    __syncthreads();
    int w = tid >> 6, l = tid & 63;
    f32x4 acc[2][2];
#pragma unroll
    for (int m = 0; m < 2; ++m)
#pragma unroll
        for (int p = 0; p < 2; ++p) acc[m][p] = (f32x4)0.f;
    int ar = l & 15, ak = (l >> 4) << 3;
#pragma unroll
    for (int ks = 0; ks < 4; ++ks) {
        bf16x8 a0 = *(const bf16x8*)&xb[ar][ks * 32 + ak];
        bf16x8 a1 = *(const bf16x8*)&xb[16 + ar][ks * 32 + ak];
#pragma unroll
        for (int p = 0; p < 2; ++p) {
            int ct = w * 2 + p;
            bf16x8 b = *(const bf16x8*)(Wswz + ((size_t)(ct * 4 + ks) * 64 + l) * 8);
            acc[0][p] = __builtin_amdgcn_mfma_f32_16x16x32_bf16(a0, b, acc[0][p], 0, 0, 0);
            acc[1][p] = __builtin_amdgcn_mfma_f32_16x16x32_bf16(a1, b, acc[1][p], 0, 0, 0);
        }
    }
#pragma unroll
    for (int p = 0; p < 2; ++p) {
        int col = (w * 2 + p) * 16 + (l & 15);
#pragma unroll
        for (int m = 0; m < 2; ++m)
#pragma unroll
            for (int r = 0; r < 4; ++r) {
                int gn = bn + m * 16 + ((l >> 4) << 2) + r;
                if (gn < N_) feat[(size_t)gn * D + col] = acc[m][p][r];
            }
    }
}

// ---------------- el/er: one wave per node ----------------
__global__ __launch_bounds__(256) void eler_kernel(const float* __restrict__ feat,
                                                   const float* __restrict__ al,
                                                   const float* __restrict__ ar,
                                                   float* __restrict__ el,
                                                   float* __restrict__ er, int N_) {
    int gw = (int)((blockIdx.x * 256 + threadIdx.x) >> 6);
    int lane = threadIdx.x & 63;
    if (gw >= N_) return;
    const float* f = feat + (size_t)gw * D;
    float a = f[lane], b = f[lane + 64];
    float pl = a * al[lane] + b * al[lane + 64];
    float pr = a * ar[lane] + b * ar[lane + 64];
#pragma unroll
    for (int m = 32; m; m >>= 1) {
        pl += __shfl_xor(pl, m);
        pr += __shfl_xor(pr, m);
    }
    if (lane == 0) { el[gw] = pl; er[gw] = pr; }
}

// ---------------- CSR build ----------------
__global__ void zero_kernel(int* __restrict__ p, int n) {
    int i = blockIdx.x * 256 + threadIdx.x;
    if (i < n) p[i] = 0;
}

__global__ void hist_kernel(const int* __restrict__ dst, int* __restrict__ cnt, int E_) {
    int i = blockIdx.x * 256 + threadIdx.x;
    if (i < E_) atomicAdd(cnt + dst[i], 1);
}

__global__ __launch_bounds__(256) void scan1_kernel(const int* __restrict__ cnt,
                                                    int* __restrict__ rp1,
                                                    int* __restrict__ bsum, int n) {
    __shared__ int ls[256];
    int b = blockIdx.x, t = threadIdx.x;
    int i0 = b * SCAN_E + t * 4;
    int v0 = (i0 + 0 < n) ? cnt[i0 + 0] : 0;
    int v1 = (i0 + 1 < n) ? cnt[i0 + 1] : 0;
    int v2 = (i0 + 2 < n) ? cnt[i0 + 2] : 0;
    int v3 = (i0 + 3 < n) ? cnt[i0 + 3] : 0;
    int s0 = v0, s1 = s0 + v1, s2 = s1 + v2, s3 = s2 + v3;
    ls[t] = s3;
    __syncthreads();
    for (int off = 1; off < 256; off <<= 1) {
        int x = (t >= off) ? ls[t - off] : 0;
        __syncthreads();
        ls[t] += x;
        __syncthreads();
    }
    int excl = ls[t] - s3;
    if (i0 + 0 < n) rp1[i0 + 0] = s0 + excl;
    if (i0 + 1 < n) rp1[i0 + 1] = s1 + excl;
    if (i0 + 2 < n) rp1[i0 + 2] = s2 + excl;
    if (i0 + 3 < n) rp1[i0 + 3] = s3 + excl;
    if (t == 255) bsum[b] = ls[255];
}

__global__ __launch_bounds__(256) void scan2_kernel(int* __restrict__ bsum, int nb) {
    __shared__ int ls[256];
    int t = threadIdx.x;
    int i0 = t * 4;
    int v0 = (i0 + 0 < nb) ? bsum[i0 + 0] : 0;
    int v1 = (i0 + 1 < nb) ? bsum[i0 + 1] : 0;
    int v2 = (i0 + 2 < nb) ? bsum[i0 + 2] : 0;
    int v3 = (i0 + 3 < nb) ? bsum[i0 + 3] : 0;
    int s0 = v0, s1 = s0 + v1, s2 = s1 + v2, s3 = s2 + v3;
    ls[t] = s3;
    __syncthreads();
    for (int off = 1; off < 256; off <<= 1) {
        int x = (t >= off) ? ls[t - off] : 0;
        __syncthreads();
        ls[t] += x;
        __syncthreads();
    }
    int excl = ls[t] - s3;
    if (i0 + 0 < nb) bsum[i0 + 0] = s0 + excl;
    if (i0 + 1 < nb) bsum[i0 + 1] = s1 + excl;
    if (i0 + 2 < nb) bsum[i0 + 2] = s2 + excl;
    if (i0 + 3 < nb) bsum[i0 + 3] = s3 + excl;
}

__global__ void scan3_kernel(int* __restrict__ rowptr, const int* __restrict__ bsum, int n) {
    int i = blockIdx.x * 256 + threadIdx.x;
    if (i < n) {
        int b = i / SCAN_E;
        if (b > 0) rowptr[i + 1] += bsum[b - 1];
    }
    if (i == 0) rowptr[0] = 0;
}

__global__ void curcopy_kernel(const int* __restrict__ rowptr, int* __restrict__ cur, int n) {
    int i = blockIdx.x * 256 + threadIdx.x;
    if (i < n) cur[i] = rowptr[i];
}

__global__ void scatter_kernel(const int* __restrict__ src, const int* __restrict__ dst,
                               int* __restrict__ cur, int* __restrict__ csrc, int E_) {
    int i = blockIdx.x * 256 + threadIdx.x;
    if (i >= E_) return;
    int d = dst[i];
    int pos = atomicAdd(cur + d, 1);
    csrc[pos] = src[i];
}

// ---------------- fused softmax + aggregation: one wave per dst node ----------------
__global__ __launch_bounds__(256) void agg_kernel(const int* __restrict__ csrc,
                                                  const int* __restrict__ rowptr,
                                                  const float* __restrict__ el,
                                                  const float* __restrict__ er,
                                                  const float* __restrict__ feat,
                                                  const float* __restrict__ bias,
                                                  float* __restrict__ rst, int N_) {
    int gw = blockIdx.x * 4 + (threadIdx.x >> 6);
    int lane = threadIdx.x & 63;
    if (gw >= N_) return;
    int r0 = rowptr[gw], r1 = rowptr[gw + 1];
    float erd = er[gw];
    float m = -3.4e38f;
    for (int base = r0; base < r1; base += 64) {
        int i = base + lane;
        float ev = -3.4e38f;
        if (i < r1) {
            int s = csrc[i];
            float v = el[s] + erd;
            ev = v > 0.f ? v : NEG_SLOPE * v;
        }
#pragma unroll
        for (int off = 32; off; off >>= 1) ev = fmaxf(ev, __shfl_xor(ev, off));
        m = fmaxf(m, ev);
    }
    float acc0 = 0.f, acc1 = 0.f, lsum = 0.f;
    for (int base = r0; base < r1; base += 64) {
        int i = base + lane;
        float ex = 0.f;
        int s = 0;
        if (i < r1) {
            s = csrc[i];
            float v = el[s] + erd;
            v = v > 0.f ? v : NEG_SLOPE * v;
            ex = expf(v - m);
        }
        lsum += ex;
        int cntc = min(64, r1 - base);
        for (int j = 0; j < cntc; ++j) {
            float exj = __shfl(ex, j);
            int sj = __shfl(s, j);
            const float* f = feat + (size_t)sj * D;
            acc0 += f[lane] * exj;
            acc1 += f[lane + 64] * exj;
        }
    }
#pragma unroll
    for (int off = 32; off; off >>= 1) lsum += __shfl_xor(lsum, off);
    float inv = (r1 > r0) ? 1.f / lsum : 0.f;
    rst[(size_t)gw * D + lane]      = acc0 * inv + bias[lane];
    rst[(size_t)gw * D + lane + 64] = acc1 * inv + bias[lane + 64];
}

// ---------------- LSTM via MFMA; LDS-transposed coalesced epilogue ----------------
#define LM 32
__global__ __launch_bounds__(256) void lstm_mfma_kernel(const float* __restrict__ x2,
                                                        const float* __restrict__ h0,
                                                        const float* __restrict__ c0,
                                                        const unsigned short* __restrict__ WTb,
                                                        const float* __restrict__ b_ih,
                                                        const float* __restrict__ b_hh,
                                                        float* __restrict__ out, int N_) {
    // region0 (16896B): xb (A-tile bf16) during MFMA, then hb (h1 f32) after.
    // region1 (16896B): cb — c0 staged coalesced, overwritten in-place with c1.
    __shared__ __align__(16) char smem[33792];
    unsigned short (*xb)[264] = reinterpret_cast<unsigned short(*)[264]>(smem);
    float (*hb)[132] = reinterpret_cast<float(*)[132]>(smem);
    float (*cb)[132] = reinterpret_cast<float(*)[132]>(smem + 16896);

    int tid = threadIdx.x;
    int bn = blockIdx.x * LM;
    // stage A-tile: [x2 | h0] 32 nodes x 256 k -> bf16 LDS
    for (int idx = tid; idx < LM * 32; idx += 256) {
        int n = idx >> 5, q = idx & 31;
        int gn = bn + n;
        unsigned short u[8];
        if (gn < N_) {
            const float* sp = (q < 16) ? (x2 + (size_t)gn * D + q * 8)
                                       : (h0 + (size_t)gn * D + (q - 16) * 8);
            float4 a = ((const float4*)sp)[0];
            float4 b = ((const float4*)sp)[1];
            u[0] = f2bf(a.x); u[1] = f2bf(a.y); u[2] = f2bf(a.z); u[3] = f2bf(a.w);
            u[4] = f2bf(b.x); u[5] = f2bf(b.y); u[6] = f2bf(b.z); u[7] = f2bf(b.w);
        } else {
#pragma unroll
            for (int i = 0; i < 8; ++i) u[i] = 0;
        }
#pragma unroll
        for (int i = 0; i < 8; ++i) xb[n][q * 8 + i] = u[i];
    }
    // stage c0 coalesced: 32 rows x 32 float4
    for (int idx = tid; idx < LM * 32; idx += 256) {
        int n = idx >> 5, q = idx & 31;
        int gn = bn + n;
        float4 v = make_float4(0.f, 0.f, 0.f, 0.f);
        if (gn < N_) v = ((const float4*)(c0 + (size_t)gn * D))[q];
        *(float4*)&cb[n][q * 4] = v;
    }
    __syncthreads();
    int w = tid >> 6, l = tid & 63;
    f32x4 acc[2][4][2];
#pragma unroll
    for (int m = 0; m < 2; ++m)
#pragma unroll
        for (int g4 = 0; g4 < 4; ++g4)
#pragma unroll
            for (int p = 0; p < 2; ++p) acc[m][g4][p] = (f32x4)0.f;
    int ar = l & 15, ak = (l >> 4) << 3;
#pragma unroll
    for (int ks = 0; ks < 8; ++ks) {
        bf16x8 a0 = *(const bf16x8*)&xb[ar][ks * 32 + ak];
        bf16x8 a1 = *(const bf16x8*)&xb[16 + ar][ks * 32 + ak];
#pragma unroll
        for (int g4 = 0; g4 < 4; ++g4)
#pragma unroll
            for (int p = 0; p < 2; ++p) {
                int ct = g4 * 8 + w * 2 + p;
                bf16x8 b = *(const bf16x8*)(WTb + ((size_t)(ct * 8 + ks) * 64 + l) * 8);
                acc[0][g4][p] = __builtin_amdgcn_mfma_f32_16x16x32_bf16(a0, b, acc[0][g4][p], 0, 0, 0);
                acc[1][g4][p] = __builtin_amdgcn_mfma_f32_16x16x32_bf16(a1, b, acc[1][g4][p], 0, 0, 0);
            }
    }
    __syncthreads();  // xb reads complete; region0 becomes hb
    // epilogue in registers; h1/c1 -> LDS at [row][col]
#pragma unroll
    for (int p = 0; p < 2; ++p) {
        int col = w * 32 + p * 16 + (l & 15);
        float bi  = b_ih[col]       + b_hh[col];
        float bf_ = b_ih[128 + col] + b_hh[128 + col];
        float bg  = b_ih[256 + col] + b_hh[256 + col];
        float bo  = b_ih[384 + col] + b_hh[384 + col];
#pragma unroll
        for (int m = 0; m < 2; ++m)
#pragma unroll
            for (int r = 0; r < 4; ++r) {
                int row = m * 16 + ((l >> 4) << 2) + r;
                float iv = acc[m][0][p][r] + bi;
                float fv = acc[m][1][p][r] + bf_;
                float gv = acc[m][2][p][r] + bg;
                float ov = acc[m][3][p][r] + bo;
                float c0v = cb[row][col];
                float c1 = fsig(fv) * c0v + fsig(iv) * ftanh(gv);
                float h1 = fsig(ov) * ftanh(c1);
                hb[row][col] = h1;
                cb[row][col] = c1;
            }
    }
    __syncthreads();
    // coalesced float4 stores: thread -> (row = tid>>3, 4 float4 chunks)
    size_t NO = (size_t)N_ * D;
    int row = tid >> 3, fq = tid & 7;
    int gn = bn + row;
    if (gn < N_) {
        size_t base = (size_t)gn * D;
#pragma unroll
        for (int k = 0; k < 4; ++k) {
            int cq = (fq + k * 8) * 4;
            float4 hv = *(const float4*)&hb[row][cq];
            float4 cv = *(const float4*)&cb[row][cq];
            *(float4*)&out[base + cq]          = hv;
            *(float4*)&out[NO + base + cq]     = hv;
            *(float4*)&out[2 * NO + base + cq] = cv;
        }
    }
}

extern "C" void kernel_launch(void* const* d_in, const int* in_sizes, int n_in,
                              void* d_out, int out_size, void* d_ws, size_t ws_size,
                              hipStream_t stream) {
    const float* x      = (const float*)d_in[0];
    const float* h      = (const float*)d_in[1];
    const float* c      = (const float*)d_in[2];
    const int*   src0   = (const int*)d_in[3];
    const int*   dst0   = (const int*)d_in[4];
    const int*   src1   = (const int*)d_in[5];
    const int*   dst1   = (const int*)d_in[6];
    const float* W      = (const float*)d_in[7];
    const float* attn_l = (const float*)d_in[8];
    const float* attn_r = (const float*)d_in[9];
    const float* gbias  = (const float*)d_in[10];
    const float* W_ih   = (const float*)d_in[11];
    const float* W_hh   = (const float*)d_in[12];
    const float* b_ih   = (const float*)d_in[13];
    const float* b_hh   = (const float*)d_in[14];
    float* out = (float*)d_out;

    const int N_ = in_sizes[1] / D;  // h is (1,N,128)
    const int E_ = in_sizes[3];
    const int nb = (N_ + SCAN_E - 1) / SCAN_E;

    // ---- transients carved out of d_out (3*N*D*4 = 153.6MB) ----
    char* ob = (char*)d_out;
    size_t ooff = 0;
    auto oalloc = [&](size_t nbytes) {
        void* p = ob + ooff;
        ooff += (nbytes + 255) & ~(size_t)255;
        return p;
    };
    float* feat = (float*)oalloc((size_t)N_ * D * 4);  // 51.2MB
    float* el   = (float*)oalloc((size_t)N_ * 4);
    float* er   = (float*)oalloc((size_t)N_ * 4);
    int*   rp0  = (int*)oalloc((size_t)(N_ + 1) * 4);
    int*   rp1  = (int*)oalloc((size_t)(N_ + 1) * 4);
    int*   cs0  = (int*)oalloc((size_t)E_ * 4);
    int*   cs1  = (int*)oalloc((size_t)E_ * 4);
    int*   cnt  = (int*)oalloc((size_t)N_ * 4);
    int*   cur  = (int*)oalloc((size_t)N_ * 4);
    int*   bsum = (int*)oalloc((size_t)1024 * 4);

    // ---- d_ws: rst + swizzled weights ----
    char* wsb = (char*)d_ws;
    size_t off = 0;
    auto alloc = [&](size_t nbytes) {
        void* p = wsb + off;
        off += (nbytes + 255) & ~(size_t)255;
        return p;
    };
    float*          rst  = (float*)alloc((size_t)N_ * D * 4);
    unsigned short* WTb  = (unsigned short*)alloc((size_t)32 * 8 * 64 * 8 * 2);  // 256KB
    unsigned short* Wswz = (unsigned short*)alloc((size_t)8 * 4 * 64 * 8 * 2);   // 32KB
    (void)ws_size;

    const int featBlocks = (N_ + FM - 1) / FM;
    const int elerBlocks = (N_ * 64 + 255) / 256;
    const int edgeBlocks = (E_ + 255) / 256;
    const int nodeBlocks = (N_ + 255) / 256;
    const int aggBlocks  = (N_ + 3) / 4;
    const int lstmBlocks = (N_ + LM - 1) / LM;

    wprep_feat_kernel<<<8, 256, 0, stream>>>(W, Wswz);
    wprep_lstm_kernel<<<64, 256, 0, stream>>>(W_ih, W_hh, WTb);

    // ---- build CSR for both graphs ----
    const int* srcs[2] = {src0, src1};
    const int* dsts[2] = {dst0, dst1};
    int* rps[2] = {rp0, rp1};
    int* css[2] = {cs0, cs1};
    for (int g = 0; g < 2; ++g) {
        zero_kernel<<<nodeBlocks, 256, 0, stream>>>(cnt, N_);
        hist_kernel<<<edgeBlocks, 256, 0, stream>>>(dsts[g], cnt, E_);
        scan1_kernel<<<nb, 256, 0, stream>>>(cnt, rps[g] + 1, bsum, N_);
        scan2_kernel<<<1, 256, 0, stream>>>(bsum, nb);
        scan3_kernel<<<nodeBlocks, 256, 0, stream>>>(rps[g], bsum, N_);
        curcopy_kernel<<<nodeBlocks, 256, 0, stream>>>(rps[g], cur, N_);
        scatter_kernel<<<edgeBlocks, 256, 0, stream>>>(srcs[g], dsts[g], cur, css[g], E_);
    }

    // ---- two GAT layers ----
    const float* layer_in = x;
    for (int L = 0; L < 2; ++L) {
        feat_mfma_kernel<<<featBlocks, 256, 0, stream>>>(layer_in, Wswz, feat, N_);
        eler_kernel<<<elerBlocks, 256, 0, stream>>>(feat, attn_l, attn_r, el, er, N_);
        agg_kernel<<<aggBlocks, 256, 0, stream>>>(css[L], rps[L], el, er, feat, gbias, rst, N_);
        layer_in = rst;
    }

    lstm_mfma_kernel<<<lstmBlocks, 256, 0, stream>>>(rst, h, c, WTb, b_ih, b_hh, out, N_);
}

// Round 9
// 783.513 us; speedup vs baseline: 3.0042x; 1.1249x over previous
//
#include <hip/hip_runtime.h>

// GeniePath: 2x GAT(H=1,D=128) + LSTM step. N=100000, E=1600000, D=OUT=128.
// Inputs f32, output f32: [h1 (N*128)] [h1 (N*128)] [c1 (N*128)]
//
// Round 8->9:
//  - feat & rst stored as bf16 (all consumers round to bf16 anyway):
//    halves agg gather + feat/rst traffic.
//  - eler fused into feat_mfma epilogue (LDS tile reuse, coalesced stores).
//  - unified CSR build over 2N virtual nodes (7 dispatches instead of 14).
//  - lstm A-tile reads x2 directly as bf16; ushort8 LDS stores.
//
// d_ws: rst bf16 (25.6MB) + WTb (256KB) + Wswz (32KB).
// d_out (153.6MB) holds transients (feat_bf, el/er, CSR arrays ~42MB),
// all dead before lstm_mfma rewrites every output element.

#define D 128
#define NEG_SLOPE 0.2f
#define SCAN_E 1024

typedef short bf16x8 __attribute__((ext_vector_type(8)));
typedef float f32x4 __attribute__((ext_vector_type(4)));
typedef unsigned short ushort8v __attribute__((ext_vector_type(8)));

__device__ __forceinline__ unsigned short f2bf(float x) {
    unsigned int b = __float_as_uint(x);
    b += 0x7fff + ((b >> 16) & 1);
    return (unsigned short)(b >> 16);
}
__device__ __forceinline__ float bf2f(unsigned short u) {
    union { unsigned int i; float f; } x;
    x.i = ((unsigned int)u) << 16;
    return x.f;
}
__device__ __forceinline__ float fsig(float x) {
    return 1.f / (1.f + __expf(-x));
}
__device__ __forceinline__ float ftanh(float x) {
    x = fminf(15.f, fmaxf(-15.f, x));
    float t = __expf(2.f * x);
    return (t - 1.f) / (t + 1.f);
}

// ---------------- weight swizzle: feat W -> B-fragment order ----------------
__global__ void wprep_feat_kernel(const float* __restrict__ W,
                                  unsigned short* __restrict__ Wswz) {
    int t = blockIdx.x * 256 + threadIdx.x;
    if (t >= 8 * 4 * 64) return;
    int ct = t >> 8, ks = (t >> 6) & 3, lane = t & 63;
    int col = ct * 16 + (lane & 15);
    int k0 = ks * 32 + ((lane >> 4) << 3);
#pragma unroll
    for (int i = 0; i < 8; ++i)
        Wswz[(size_t)t * 8 + i] = f2bf(W[(k0 + i) * D + col]);
}

// ---------------- weight swizzle: LSTM Wcat -> B-fragment order ----------------
__global__ void wprep_lstm_kernel(const float* __restrict__ W_ih,
                                  const float* __restrict__ W_hh,
                                  unsigned short* __restrict__ WTb) {
    int t = blockIdx.x * 256 + threadIdx.x;
    if (t >= 32 * 8 * 64) return;
    int ct = t >> 9, ks = (t >> 6) & 7, lane = t & 63;
    int col = ct * 16 + (lane & 15);
    int k0 = ks * 32 + ((lane >> 4) << 3);
#pragma unroll
    for (int i = 0; i < 8; ++i) {
        int k = k0 + i;
        float v = (k < 128) ? W_ih[col * 128 + k] : W_hh[col * 128 + (k - 128)];
        WTb[(size_t)t * 8 + i] = f2bf(v);
    }
}

// ---- feat = x @ W via MFMA; bf16 out; fused el/er ----
// BF=true: input is bf16 (rst); BF=false: input is f32 (x).
#define FM 32
template <bool BF>
__global__ __launch_bounds__(256) void feat_mfma_kernel(const void* __restrict__ xin_,
                                                        const unsigned short* __restrict__ Wswz,
                                                        unsigned short* __restrict__ feat,
                                                        const float* __restrict__ al,
                                                        const float* __restrict__ ar,
                                                        float* __restrict__ el,
                                                        float* __restrict__ er, int N_) {
    __shared__ unsigned short sm[FM][136];  // A-tile, then output tile (overlay)
    int tid = threadIdx.x;
    int bn = blockIdx.x * FM;
    for (int idx = tid; idx < FM * 16; idx += 256) {
        int n = idx >> 4, q = idx & 15;
        int gn = bn + n;
        ushort8v u = (ushort8v)0;
        if (gn < N_) {
            if constexpr (BF) {
                u = *(const ushort8v*)((const unsigned short*)xin_ + (size_t)gn * D + q * 8);
            } else {
                const float* sp = (const float*)xin_ + (size_t)gn * D + q * 8;
                float4 a = ((const float4*)sp)[0];
                float4 b = ((const float4*)sp)[1];
                u[0] = f2bf(a.x); u[1] = f2bf(a.y); u[2] = f2bf(a.z); u[3] = f2bf(a.w);
                u[4] = f2bf(b.x); u[5] = f2bf(b.y); u[6] = f2bf(b.z); u[7] = f2bf(b.w);
            }
        }
        *(ushort8v*)&sm[n][q * 8] = u;
    }
    __syncthreads();
    int w = tid >> 6, l = tid & 63;
    f32x4 acc[2][2];
#pragma unroll
    for (int m = 0; m < 2; ++m)
#pragma unroll
        for (int p = 0; p < 2; ++p) acc[m][p] = (f32x4)0.f;
    int ar_ = l & 15, ak = (l >> 4) << 3;
#pragma unroll
    for (int ks = 0; ks < 4; ++ks) {
        bf16x8 a0 = *(const bf16x8*)&sm[ar_][ks * 32 + ak];
        bf16x8 a1 = *(const bf16x8*)&sm[16 + ar_][ks * 32 + ak];
#pragma unroll
        for (int p = 0; p < 2; ++p) {
            int ct = w * 2 + p;
            bf16x8 b = *(const bf16x8*)(Wswz + ((size_t)(ct * 4 + ks) * 64 + l) * 8);
            acc[0][p] = __builtin_amdgcn_mfma_f32_16x16x32_bf16(a0, b, acc[0][p], 0, 0, 0);
            acc[1][p] = __builtin_amdgcn_mfma_f32_16x16x32_bf16(a1, b, acc[1][p], 0, 0, 0);
        }
    }
    __syncthreads();  // A-tile reads done; overlay output tile
#pragma unroll
    for (int p = 0; p < 2; ++p) {
        int col = (w * 2 + p) * 16 + (l & 15);
#pragma unroll
        for (int m = 0; m < 2; ++m)
#pragma unroll
            for (int r = 0; r < 4; ++r) {
                int row = m * 16 + ((l >> 4) << 2) + r;
                sm[row][col] = f2bf(acc[m][p][r]);
            }
    }
    __syncthreads();
    // coalesced bf16 stores (16B per thread x2)
#pragma unroll
    for (int s = 0; s < 2; ++s) {
        int idx = tid + s * 256;
        int row = idx >> 4, q = idx & 15;
        int gn = bn + row;
        if (gn < N_)
            *(ushort8v*)(feat + (size_t)gn * D + q * 8) = *(const ushort8v*)&sm[row][q * 8];
    }
    // fused el/er: 8 lanes per row, 16 cols per lane
    {
        int row = w * 8 + (l >> 3);
        int c0 = (l & 7) * 16;
        int gn = bn + row;
        float pl = 0.f, pr = 0.f;
#pragma unroll
        for (int i = 0; i < 16; ++i) {
            float v = bf2f(sm[row][c0 + i]);
            pl += v * al[c0 + i];
            pr += v * ar[c0 + i];
        }
        pl += __shfl_xor(pl, 1); pr += __shfl_xor(pr, 1);
        pl += __shfl_xor(pl, 2); pr += __shfl_xor(pr, 2);
        pl += __shfl_xor(pl, 4); pr += __shfl_xor(pr, 4);
        if ((l & 7) == 0 && gn < N_) { el[gn] = pl; er[gn] = pr; }
    }
}

// ---------------- unified CSR build (2N virtual nodes, 2E edges) ----------------
__global__ void zero_kernel(int* __restrict__ p, int n) {
    int i = blockIdx.x * 256 + threadIdx.x;
    if (i < n) p[i] = 0;
}

__global__ void hist2_kernel(const int* __restrict__ dst0, const int* __restrict__ dst1,
                             int* __restrict__ cnt, int E_, int N_) {
    int i = blockIdx.x * 256 + threadIdx.x;
    if (i >= 2 * E_) return;
    int d = (i < E_) ? dst0[i] : (dst1[i - E_] + N_);
    atomicAdd(cnt + d, 1);
}

__global__ __launch_bounds__(256) void scan1_kernel(const int* __restrict__ cnt,
                                                    int* __restrict__ rp1,
                                                    int* __restrict__ bsum, int n) {
    __shared__ int ls[256];
    int b = blockIdx.x, t = threadIdx.x;
    int i0 = b * SCAN_E + t * 4;
    int v0 = (i0 + 0 < n) ? cnt[i0 + 0] : 0;
    int v1 = (i0 + 1 < n) ? cnt[i0 + 1] : 0;
    int v2 = (i0 + 2 < n) ? cnt[i0 + 2] : 0;
    int v3 = (i0 + 3 < n) ? cnt[i0 + 3] : 0;
    int s0 = v0, s1 = s0 + v1, s2 = s1 + v2, s3 = s2 + v3;
    ls[t] = s3;
    __syncthreads();
    for (int off = 1; off < 256; off <<= 1) {
        int x = (t >= off) ? ls[t - off] : 0;
        __syncthreads();
        ls[t] += x;
        __syncthreads();
    }
    int excl = ls[t] - s3;
    if (i0 + 0 < n) rp1[i0 + 0] = s0 + excl;
    if (i0 + 1 < n) rp1[i0 + 1] = s1 + excl;
    if (i0 + 2 < n) rp1[i0 + 2] = s2 + excl;
    if (i0 + 3 < n) rp1[i0 + 3] = s3 + excl;
    if (t == 255) bsum[b] = ls[255];
}

__global__ __launch_bounds__(256) void scan2_kernel(int* __restrict__ bsum, int nb) {
    __shared__ int ls[256];
    int t = threadIdx.x;
    int i0 = t * 4;
    int v0 = (i0 + 0 < nb) ? bsum[i0 + 0] : 0;
    int v1 = (i0 + 1 < nb) ? bsum[i0 + 1] : 0;
    int v2 = (i0 + 2 < nb) ? bsum[i0 + 2] : 0;
    int v3 = (i0 + 3 < nb) ? bsum[i0 + 3] : 0;
    int s0 = v0, s1 = s0 + v1, s2 = s1 + v2, s3 = s2 + v3;
    ls[t] = s3;
    __syncthreads();
    for (int off = 1; off < 256; off <<= 1) {
        int x = (t >= off) ? ls[t - off] : 0;
        __syncthreads();
        ls[t] += x;
        __syncthreads();
    }
    int excl = ls[t] - s3;
    if (i0 + 0 < nb) bsum[i0 + 0] = s0 + excl;
    if (i0 + 1 < nb) bsum[i0 + 1] = s1 + excl;
    if (i0 + 2 < nb) bsum[i0 + 2] = s2 + excl;
    if (i0 + 3 < nb) bsum[i0 + 3] = s3 + excl;
}

// finalize rowptr and init cursors: rp[0]=0; rp[i+1]+=bsum; cur[i]=rp[i]
__global__ void scan3_kernel(int* __restrict__ rowptr, int* __restrict__ cur,
                             const int* __restrict__ bsum, int n) {
    int i = blockIdx.x * 256 + threadIdx.x;
    if (i >= n) return;
    int b = i / SCAN_E;
    int v = rowptr[i + 1] + ((b > 0) ? bsum[b - 1] : 0);
    rowptr[i + 1] = v;
    if (i + 1 < n) cur[i + 1] = v;
    if (i == 0) { rowptr[0] = 0; cur[0] = 0; }
}

__global__ void scatter2_kernel(const int* __restrict__ src0, const int* __restrict__ src1,
                                const int* __restrict__ dst0, const int* __restrict__ dst1,
                                int* __restrict__ cur, int* __restrict__ csrc,
                                int E_, int N_) {
    int i = blockIdx.x * 256 + threadIdx.x;
    if (i >= 2 * E_) return;
    int s, d;
    if (i < E_) { s = src0[i]; d = dst0[i]; }
    else        { s = src1[i - E_]; d = dst1[i - E_] + N_; }
    int pos = atomicAdd(cur + d, 1);
    csrc[pos] = s;
}

// ---- fused softmax + aggregation: one wave per dst node; bf16 feat/rst ----
__global__ __launch_bounds__(256) void agg_kernel(const int* __restrict__ csrc,
                                                  const int* __restrict__ rowptr,
                                                  const float* __restrict__ el,
                                                  const float* __restrict__ er,
                                                  const unsigned short* __restrict__ feat,
                                                  const float* __restrict__ bias,
                                                  unsigned short* __restrict__ rst, int N_) {
    int gw = blockIdx.x * 4 + (threadIdx.x >> 6);
    int lane = threadIdx.x & 63;
    if (gw >= N_) return;
    int r0 = rowptr[gw], r1 = rowptr[gw + 1];
    float erd = er[gw];
    float m = -3.4e38f;
    for (int base = r0; base < r1; base += 64) {
        int i = base + lane;
        float ev = -3.4e38f;
        if (i < r1) {
            int s = csrc[i];
            float v = el[s] + erd;
            ev = v > 0.f ? v : NEG_SLOPE * v;
        }
#pragma unroll
        for (int off = 32; off; off >>= 1) ev = fmaxf(ev, __shfl_xor(ev, off));
        m = fmaxf(m, ev);
    }
    float acc0 = 0.f, acc1 = 0.f, lsum = 0.f;
    for (int base = r0; base < r1; base += 64) {
        int i = base + lane;
        float ex = 0.f;
        int s = 0;
        if (i < r1) {
            s = csrc[i];
            float v = el[s] + erd;
            v = v > 0.f ? v : NEG_SLOPE * v;
            ex = expf(v - m);
        }
        lsum += ex;
        int cntc = min(64, r1 - base);
        for (int j = 0; j < cntc; ++j) {
            float exj = __shfl(ex, j);
            int sj = __shfl(s, j);
            unsigned int fv = *(const unsigned int*)(feat + (size_t)sj * D + 2 * lane);
            acc0 += bf2f((unsigned short)(fv & 0xffffu)) * exj;
            acc1 += bf2f((unsigned short)(fv >> 16)) * exj;
        }
    }
#pragma unroll
    for (int off = 32; off; off >>= 1) lsum += __shfl_xor(lsum, off);
    float inv = (r1 > r0) ? 1.f / lsum : 0.f;
    float v0 = acc0 * inv + bias[2 * lane];
    float v1 = acc1 * inv + bias[2 * lane + 1];
    unsigned int pk = (unsigned int)f2bf(v0) | ((unsigned int)f2bf(v1) << 16);
    *(unsigned int*)(rst + (size_t)gw * D + 2 * lane) = pk;
}

// ---------------- LSTM via MFMA; LDS-transposed coalesced epilogue ----------------
#define LM 32
__global__ __launch_bounds__(256) void lstm_mfma_kernel(const unsigned short* __restrict__ x2,
                                                        const float* __restrict__ h0,
                                                        const float* __restrict__ c0,
                                                        const unsigned short* __restrict__ WTb,
                                                        const float* __restrict__ b_ih,
                                                        const float* __restrict__ b_hh,
                                                        float* __restrict__ out, int N_) {
    __shared__ __align__(16) char smem[33792];
    unsigned short (*xb)[264] = reinterpret_cast<unsigned short(*)[264]>(smem);
    float (*hb)[132] = reinterpret_cast<float(*)[132]>(smem);
    float (*cb)[132] = reinterpret_cast<float(*)[132]>(smem + 16896);

    int tid = threadIdx.x;
    int bn = blockIdx.x * LM;
    // stage A-tile: [x2 bf16 | h0 f32->bf16], 32 nodes x 256 k
    for (int idx = tid; idx < LM * 32; idx += 256) {
        int n = idx >> 5, q = idx & 31;
        int gn = bn + n;
        ushort8v u = (ushort8v)0;
        if (gn < N_) {
            if (q < 16) {
                u = *(const ushort8v*)(x2 + (size_t)gn * D + q * 8);
            } else {
                const float* sp = h0 + (size_t)gn * D + (q - 16) * 8;
                float4 a = ((const float4*)sp)[0];
                float4 b = ((const float4*)sp)[1];
                u[0] = f2bf(a.x); u[1] = f2bf(a.y); u[2] = f2bf(a.z); u[3] = f2bf(a.w);
                u[4] = f2bf(b.x); u[5] = f2bf(b.y); u[6] = f2bf(b.z); u[7] = f2bf(b.w);
            }
        }
        *(ushort8v*)&xb[n][q * 8] = u;
    }
    // stage c0 coalesced
    for (int idx = tid; idx < LM * 32; idx += 256) {
        int n = idx >> 5, q = idx & 31;
        int gn = bn + n;
        float4 v = make_float4(0.f, 0.f, 0.f, 0.f);
        if (gn < N_) v = ((const float4*)(c0 + (size_t)gn * D))[q];
        *(float4*)&cb[n][q * 4] = v;
    }
    __syncthreads();
    int w = tid >> 6, l = tid & 63;
    f32x4 acc[2][4][2];
#pragma unroll
    for (int m = 0; m < 2; ++m)
#pragma unroll
        for (int g4 = 0; g4 < 4; ++g4)
#pragma unroll
            for (int p = 0; p < 2; ++p) acc[m][g4][p] = (f32x4)0.f;
    int ar = l & 15, ak = (l >> 4) << 3;
#pragma unroll
    for (int ks = 0; ks < 8; ++ks) {
        bf16x8 a0 = *(const bf16x8*)&xb[ar][ks * 32 + ak];
        bf16x8 a1 = *(const bf16x8*)&xb[16 + ar][ks * 32 + ak];
#pragma unroll
        for (int g4 = 0; g4 < 4; ++g4)
#pragma unroll
            for (int p = 0; p < 2; ++p) {
                int ct = g4 * 8 + w * 2 + p;
                bf16x8 b = *(const bf16x8*)(WTb + ((size_t)(ct * 8 + ks) * 64 + l) * 8);
                acc[0][g4][p] = __builtin_amdgcn_mfma_f32_16x16x32_bf16(a0, b, acc[0][g4][p], 0, 0, 0);
                acc[1][g4][p] = __builtin_amdgcn_mfma_f32_16x16x32_bf16(a1, b, acc[1][g4][p], 0, 0, 0);
            }
    }
    __syncthreads();  // xb reads complete; region0 becomes hb
#pragma unroll
    for (int p = 0; p < 2; ++p) {
        int col = w * 32 + p * 16 + (l & 15);
        float bi  = b_ih[col]       + b_hh[col];
        float bf_ = b_ih[128 + col] + b_hh[128 + col];
        float bg  = b_ih[256 + col] + b_hh[256 + col];
        float bo  = b_ih[384 + col] + b_hh[384 + col];
#pragma unroll
        for (int m = 0; m < 2; ++m)
#pragma unroll
            for (int r = 0; r < 4; ++r) {
                int row = m * 16 + ((l >> 4) << 2) + r;
                float iv = acc[m][0][p][r] + bi;
                float fv = acc[m][1][p][r] + bf_;
                float gv = acc[m][2][p][r] + bg;
                float ov = acc[m][3][p][r] + bo;
                float c0v = cb[row][col];
                float c1 = fsig(fv) * c0v + fsig(iv) * ftanh(gv);
                float h1 = fsig(ov) * ftanh(c1);
                hb[row][col] = h1;
                cb[row][col] = c1;
            }
    }
    __syncthreads();
    size_t NO = (size_t)N_ * D;
    int row = tid >> 3, fq = tid & 7;
    int gn = bn + row;
    if (gn < N_) {
        size_t base = (size_t)gn * D;
#pragma unroll
        for (int k = 0; k < 4; ++k) {
            int cq = (fq + k * 8) * 4;
            float4 hv = *(const float4*)&hb[row][cq];
            float4 cv = *(const float4*)&cb[row][cq];
            *(float4*)&out[base + cq]          = hv;
            *(float4*)&out[NO + base + cq]     = hv;
            *(float4*)&out[2 * NO + base + cq] = cv;
        }
    }
}

extern "C" void kernel_launch(void* const* d_in, const int* in_sizes, int n_in,
                              void* d_out, int out_size, void* d_ws, size_t ws_size,
                              hipStream_t stream) {
    const float* x      = (const float*)d_in[0];
    const float* h      = (const float*)d_in[1];
    const float* c      = (const float*)d_in[2];
    const int*   src0   = (const int*)d_in[3];
    const int*   dst0   = (const int*)d_in[4];
    const int*   src1   = (const int*)d_in[5];
    const int*   dst1   = (const int*)d_in[6];
    const float* W      = (const float*)d_in[7];
    const float* attn_l = (const float*)d_in[8];
    const float* attn_r = (const float*)d_in[9];
    const float* gbias  = (const float*)d_in[10];
    const float* W_ih   = (const float*)d_in[11];
    const float* W_hh   = (const float*)d_in[12];
    const float* b_ih   = (const float*)d_in[13];
    const float* b_hh   = (const float*)d_in[14];
    float* out = (float*)d_out;

    const int N_ = in_sizes[1] / D;  // h is (1,N,128)
    const int E_ = in_sizes[3];
    const int n2 = 2 * N_;
    const int nb2 = (n2 + SCAN_E - 1) / SCAN_E;

    // ---- transients carved out of d_out (3*N*D*4 = 153.6MB) ----
    char* ob = (char*)d_out;
    size_t ooff = 0;
    auto oalloc = [&](size_t nbytes) {
        void* p = ob + ooff;
        ooff += (nbytes + 255) & ~(size_t)255;
        return p;
    };
    unsigned short* featb = (unsigned short*)oalloc((size_t)N_ * D * 2);  // 25.6MB
    float* el   = (float*)oalloc((size_t)N_ * 4);
    float* er   = (float*)oalloc((size_t)N_ * 4);
    int*   rp01 = (int*)oalloc((size_t)(n2 + 1) * 4);
    int*   cs01 = (int*)oalloc((size_t)2 * E_ * 4);  // 12.8MB
    int*   cnt  = (int*)oalloc((size_t)n2 * 4);
    int*   cur  = (int*)oalloc((size_t)n2 * 4);
    int*   bsum = (int*)oalloc((size_t)1024 * 4);

    // ---- d_ws: rst bf16 + swizzled weights ----
    char* wsb = (char*)d_ws;
    size_t off = 0;
    auto alloc = [&](size_t nbytes) {
        void* p = wsb + off;
        off += (nbytes + 255) & ~(size_t)255;
        return p;
    };
    unsigned short* rst  = (unsigned short*)alloc((size_t)N_ * D * 2);
    unsigned short* WTb  = (unsigned short*)alloc((size_t)32 * 8 * 64 * 8 * 2);
    unsigned short* Wswz = (unsigned short*)alloc((size_t)8 * 4 * 64 * 8 * 2);
    (void)ws_size;

    const int featBlocks = (N_ + FM - 1) / FM;
    const int e2Blocks   = (2 * E_ + 255) / 256;
    const int n2Blocks   = (n2 + 255) / 256;
    const int aggBlocks  = (N_ + 3) / 4;
    const int lstmBlocks = (N_ + LM - 1) / LM;

    wprep_feat_kernel<<<8, 256, 0, stream>>>(W, Wswz);
    wprep_lstm_kernel<<<64, 256, 0, stream>>>(W_ih, W_hh, WTb);

    // ---- unified CSR build ----
    zero_kernel<<<n2Blocks, 256, 0, stream>>>(cnt, n2);
    hist2_kernel<<<e2Blocks, 256, 0, stream>>>(dst0, dst1, cnt, E_, N_);
    scan1_kernel<<<nb2, 256, 0, stream>>>(cnt, rp01 + 1, bsum, n2);
    scan2_kernel<<<1, 256, 0, stream>>>(bsum, nb2);
    scan3_kernel<<<n2Blocks, 256, 0, stream>>>(rp01, cur, bsum, n2);
    scatter2_kernel<<<e2Blocks, 256, 0, stream>>>(src0, src1, dst0, dst1, cur, cs01, E_, N_);

    // ---- two GAT layers ----
    for (int L = 0; L < 2; ++L) {
        if (L == 0)
            feat_mfma_kernel<false><<<featBlocks, 256, 0, stream>>>(x, Wswz, featb,
                                                                    attn_l, attn_r, el, er, N_);
        else
            feat_mfma_kernel<true><<<featBlocks, 256, 0, stream>>>(rst, Wswz, featb,
                                                                   attn_l, attn_r, el, er, N_);
        agg_kernel<<<aggBlocks, 256, 0, stream>>>(cs01, rp01 + (size_t)L * N_, el, er,
                                                  featb, gbias, rst, N_);
    }

    lstm_mfma_kernel<<<lstmBlocks, 256, 0, stream>>>(rst, h, c, WTb, b_ih, b_hh, out, N_);
}